// Round 3
// baseline (444.018 us; speedup 1.0000x reference)
//
#include <hip/hip_runtime.h>
#include <hip/hip_bf16.h>
#include <math.h>

#define D_MODEL   1024
#define D_STATE   128
#define HEADDIM   64
#define CHUNK     64
#define D_INNER   2048
#define NHEADS    32
#define D_IN_PROJ 4384   // 2*2048 + 2*128 + 32
#define CONV_CH   2304   // 2048 + 256
#define RCOLS     2336   // CONV_CH + NHEADS (xBC-raw + dt-raw columns)
#define WINT_ROWS 4608   // D_IN_PROJ padded to 18 col-tiles of 256
#define BATCH     2
#define SEQ       4096
#define NCHUNK    64     // SEQ / CHUNK
#define ROWS      (BATCH*SEQ)   // 8192
#define EPS_RMS   1e-5f

typedef __hip_bfloat16 bf16;
typedef __bf16 bf16x8_t __attribute__((ext_vector_type(8)));
typedef float  f32x4_t  __attribute__((ext_vector_type(4)));

__device__ __forceinline__ float siluf_(float x){ return x/(1.f+expf(-x)); }
__device__ __forceinline__ float ldf(const float* p){ return *p; }
__device__ __forceinline__ float ldf(const bf16* p){ return __bfloat162float(*p); }
__device__ __forceinline__ void  stf(float* p, float v){ *p = v; }
__device__ __forceinline__ void  stf(bf16* p, float v){ *p = __float2bfloat16(v); }

__device__ __forceinline__ __bf16 tobf(float v){
    __hip_bfloat16 t = __float2bfloat16(v);
    return *reinterpret_cast<__bf16*>(&t);
}
__device__ __forceinline__ unsigned short bfbits(float v){
    __hip_bfloat16 t = __float2bfloat16(v);
    return *reinterpret_cast<unsigned short*>(&t);
}
__device__ __forceinline__ float bfbits2f(unsigned short u){
    union { unsigned u; float f; } cv; cv.u = ((unsigned)u) << 16; return cv.f;
}

// async global->LDS, 16 B per lane; LDS dest is wave-uniform base + lane*16.
__device__ __forceinline__ void async16(const void* g, void* l) {
    __builtin_amdgcn_global_load_lds(
        (const __attribute__((address_space(1))) unsigned int*)g,
        (__attribute__((address_space(3))) unsigned int*)l, 16, 0, 0);
}

// ---------------------------------------------------------------------------
// m201-geometry MFMA core: 256x256 tile, BK=64, 8 waves (2M x 4N), per-wave
// 128x64 output (8x4 frags, 64 MFMA/K-tile), 2-deep LDS double buffer
// (128 KiB), 4 phases/K-tile of 16 MFMA each.
// Staging: 8 chunks (64 rows x 128 B = one global_load_lds each) per K-tile,
// issue order per tile t (into buf^1, for tile t+1):
//   P0: A0,A2,B0   P1: B1,B2,B3   P2: A1   P3: A3
// Waits (before the phase-closing barrier, so the barrier publishes them):
//   P1-end: vmcnt(6)  -> guarantees A1,A3(t) landed before P2's ds_read
//   P3-end: vmcnt(2)  -> guarantees A0,A2,B0..B3(t+1) before next P0 ds_read
// Last tile stages nothing -> constants drop to 0.
// LDS XOR-swizzle byte ^= (row&7)<<4, inverse pre-applied to the global
// source (rule #21); measured conflict-free in round 1.
// ---------------------------------------------------------------------------
struct Core256 {
    f32x4_t acc[8][4];

    __device__ __forceinline__ void stg(const bf16* __restrict__ g, int ld,
                                        int rbase, int kk, __bf16* buf, int c,
                                        int tid, int lcb) {
        const char* src = (const char*)(g + (size_t)(rbase + c * 64 + (tid >> 3)) * ld + kk) + lcb;
        async16(src, buf + c * 4096 + ((tid >> 6) << 9));
    }

    __device__ __forceinline__ void run(const bf16* __restrict__ A,
                                        const bf16* __restrict__ Bt,
                                        int lda, int ldb,
                                        int row0, int col0, int k0, int nt,
                                        __bf16* As, __bf16* Bs, int tid) {
        const int wave = tid >> 6, lane = tid & 63;
        const int quad = lane >> 4, l16 = lane & 15;
        const int wm = wave >> 2, wn = wave & 3;
        const int lcb = (((tid & 7) ^ ((tid >> 3) & 7)) << 4);
        const int xb = (l16 & 7) << 4;

#pragma unroll
        for (int i = 0; i < 8; ++i)
#pragma unroll
            for (int j = 0; j < 4; ++j) acc[i][j] = (f32x4_t){0.f, 0.f, 0.f, 0.f};

        int aoff[8][2], boff[4][2];
#pragma unroll
        for (int ks = 0; ks < 2; ++ks) {
            const int cb = ((ks << 6) | (quad << 4)) ^ xb;
#pragma unroll
            for (int mi = 0; mi < 8; ++mi)
                aoff[mi][ks] = (wm * 128 + mi * 16 + l16) * 128 + cb;
#pragma unroll
            for (int ni = 0; ni < 4; ++ni)
                boff[ni][ks] = (wn * 64 + ni * 16 + l16) * 128 + cb;
        }

        // prologue: tile 0, order A0,A2,B0,B1,B2,B3,A1,A3
        stg(A,  lda, row0, k0, As, 0, tid, lcb);
        stg(A,  lda, row0, k0, As, 2, tid, lcb);
        stg(Bt, ldb, col0, k0, Bs, 0, tid, lcb);
        stg(Bt, ldb, col0, k0, Bs, 1, tid, lcb);
        stg(Bt, ldb, col0, k0, Bs, 2, tid, lcb);
        stg(Bt, ldb, col0, k0, Bs, 3, tid, lcb);
        stg(A,  lda, row0, k0, As, 1, tid, lcb);
        stg(A,  lda, row0, k0, As, 3, tid, lcb);
        asm volatile("s_waitcnt vmcnt(2)" ::: "memory");
        __builtin_amdgcn_s_barrier();
        asm volatile("" ::: "memory");

        for (int t = 0; t < nt; ++t) {
            const bool st = (t + 1 < nt);
            const int kk = k0 + (t + 1) * 64;
            const int cur = t & 1;
            const char* Ab = (const char*)(As + cur * 16384);
            const char* Bb = (const char*)(Bs + cur * 16384);
            __bf16* Asb = As + (cur ^ 1) * 16384;
            __bf16* Bsb = Bs + (cur ^ 1) * 16384;
            bf16x8_t af[4][2], b0r[2][2], b1r[2][2];

            // ---------------- P0: read A-lo + B-lo; stage A0,A2,B0(t+1)
#pragma unroll
            for (int mi = 0; mi < 4; ++mi)
#pragma unroll
                for (int ks = 0; ks < 2; ++ks)
                    af[mi][ks] = *(const bf16x8_t*)(Ab + aoff[mi][ks]);
#pragma unroll
            for (int ni = 0; ni < 2; ++ni)
#pragma unroll
                for (int ks = 0; ks < 2; ++ks)
                    b0r[ni][ks] = *(const bf16x8_t*)(Bb + boff[ni][ks]);
            if (st) {
                stg(A,  lda, row0, kk, Asb, 0, tid, lcb);
                stg(A,  lda, row0, kk, Asb, 2, tid, lcb);
                stg(Bt, ldb, col0, kk, Bsb, 0, tid, lcb);
            }
            asm volatile("" ::: "memory");
            __builtin_amdgcn_s_barrier();
            asm volatile("s_waitcnt lgkmcnt(0)" ::: "memory");
            __builtin_amdgcn_s_setprio(1);
#pragma unroll
            for (int ks = 0; ks < 2; ++ks)
#pragma unroll
                for (int mi = 0; mi < 4; ++mi)
#pragma unroll
                    for (int ni = 0; ni < 2; ++ni)
                        acc[mi][ni] = __builtin_amdgcn_mfma_f32_16x16x32_bf16(
                            af[mi][ks], b0r[ni][ks], acc[mi][ni], 0, 0, 0);
            __builtin_amdgcn_s_setprio(0);
            __builtin_amdgcn_s_barrier();
            asm volatile("" ::: "memory");

            // ---------------- P1: read B-hi; stage B1,B2,B3(t+1); vmcnt(6)
#pragma unroll
            for (int ni = 0; ni < 2; ++ni)
#pragma unroll
                for (int ks = 0; ks < 2; ++ks)
                    b1r[ni][ks] = *(const bf16x8_t*)(Bb + boff[2 + ni][ks]);
            if (st) {
                stg(Bt, ldb, col0, kk, Bsb, 1, tid, lcb);
                stg(Bt, ldb, col0, kk, Bsb, 2, tid, lcb);
                stg(Bt, ldb, col0, kk, Bsb, 3, tid, lcb);
                asm volatile("s_waitcnt vmcnt(6)" ::: "memory");
            } else {
                asm volatile("s_waitcnt vmcnt(0)" ::: "memory");
            }
            __builtin_amdgcn_s_barrier();
            asm volatile("s_waitcnt lgkmcnt(0)" ::: "memory");
            __builtin_amdgcn_s_setprio(1);
#pragma unroll
            for (int ks = 0; ks < 2; ++ks)
#pragma unroll
                for (int mi = 0; mi < 4; ++mi)
#pragma unroll
                    for (int ni = 0; ni < 2; ++ni)
                        acc[mi][2 + ni] = __builtin_amdgcn_mfma_f32_16x16x32_bf16(
                            af[mi][ks], b1r[ni][ks], acc[mi][2 + ni], 0, 0, 0);
            __builtin_amdgcn_s_setprio(0);
            __builtin_amdgcn_s_barrier();
            asm volatile("" ::: "memory");

            // ---------------- P2: read A-hi; stage A1(t+1)
#pragma unroll
            for (int mi = 0; mi < 4; ++mi)
#pragma unroll
                for (int ks = 0; ks < 2; ++ks)
                    af[mi][ks] = *(const bf16x8_t*)(Ab + aoff[4 + mi][ks]);
            if (st) stg(A, lda, row0, kk, Asb, 1, tid, lcb);
            asm volatile("" ::: "memory");
            __builtin_amdgcn_s_barrier();
            asm volatile("s_waitcnt lgkmcnt(0)" ::: "memory");
            __builtin_amdgcn_s_setprio(1);
#pragma unroll
            for (int ks = 0; ks < 2; ++ks)
#pragma unroll
                for (int mi = 0; mi < 4; ++mi)
#pragma unroll
                    for (int ni = 0; ni < 2; ++ni)
                        acc[4 + mi][2 + ni] = __builtin_amdgcn_mfma_f32_16x16x32_bf16(
                            af[mi][ks], b1r[ni][ks], acc[4 + mi][2 + ni], 0, 0, 0);
            __builtin_amdgcn_s_setprio(0);
            __builtin_amdgcn_s_barrier();
            asm volatile("" ::: "memory");

            // ---------------- P3: no reads; stage A3(t+1); vmcnt(2)
            if (st) {
                stg(A, lda, row0, kk, Asb, 3, tid, lcb);
                asm volatile("s_waitcnt vmcnt(2)" ::: "memory");
            }
            __builtin_amdgcn_s_barrier();
            asm volatile("" ::: "memory");
            __builtin_amdgcn_s_setprio(1);
#pragma unroll
            for (int ks = 0; ks < 2; ++ks)
#pragma unroll
                for (int mi = 0; mi < 4; ++mi)
#pragma unroll
                    for (int ni = 0; ni < 2; ++ni)
                        acc[4 + mi][ni] = __builtin_amdgcn_mfma_f32_16x16x32_bf16(
                            af[mi][ks], b0r[ni][ks], acc[4 + mi][ni], 0, 0, 0);
            __builtin_amdgcn_s_setprio(0);
            __builtin_amdgcn_s_barrier();
            asm volatile("" ::: "memory");
        }
    }
};

// Fused Z|R GEMM: grid (32 row-tiles of 256, 18 col-tiles of 256).
__global__ __launch_bounds__(512) void gemm_zr_fused(const bf16* __restrict__ A,
                                                     const bf16* __restrict__ Bt,
                                                     bf16* __restrict__ Z,
                                                     bf16* __restrict__ R) {
    __shared__ __align__(16) __bf16 As[2 * 16384];   // 64 KiB
    __shared__ __align__(16) __bf16 Bs[2 * 16384];   // 64 KiB
    const int tid = threadIdx.x;
    const int row0 = blockIdx.x * 256;
    const int ct   = blockIdx.y;
    Core256 g;
    g.run(A, Bt, D_MODEL, D_MODEL, row0, ct * 256, 0, 16, As, Bs, tid);

    const int wave = tid >> 6, lane = tid & 63;
    const int quad = lane >> 4, l16 = lane & 15;
    const int wm = wave >> 2, wn = wave & 3;
    bf16* Cp; int ldc_, cl0, ncols;
    if (ct < 8) { Cp = Z; ldc_ = D_INNER; cl0 = ct * 256;           ncols = D_INNER; }
    else        { Cp = R; ldc_ = RCOLS;   cl0 = ct * 256 - D_INNER; ncols = RCOLS; }
#pragma unroll
    for (int ni = 0; ni < 4; ++ni) {
        int gc = cl0 + wn * 64 + ni * 16 + l16;
        if (gc >= ncols) continue;
#pragma unroll
        for (int mi = 0; mi < 8; ++mi)
#pragma unroll
            for (int r = 0; r < 4; ++r) {
                int gr = row0 + wm * 128 + mi * 16 + quad * 4 + r;
                stf(&Cp[(size_t)gr * ldc_ + gc], g.acc[mi][ni][r]);
            }
    }
}

// Out GEMM, split-K=2: partial[kz][m][n] fp32. grid (32, 4, 2) = 256 blocks.
__global__ __launch_bounds__(512) void gemm_out_splitk(const bf16* __restrict__ A,
                                                       const bf16* __restrict__ Bt,
                                                       float* __restrict__ part) {
    __shared__ __align__(16) __bf16 As[2 * 16384];
    __shared__ __align__(16) __bf16 Bs[2 * 16384];
    const int tid = threadIdx.x;
    const int row0 = blockIdx.x * 256;
    const int col0 = blockIdx.y * 256;
    const int kz   = blockIdx.z;
    Core256 g;
    g.run(A, Bt, D_INNER, D_INNER, row0, col0, kz * 1024, 16, As, Bs, tid);

    const int wave = tid >> 6, lane = tid & 63;
    const int quad = lane >> 4, l16 = lane & 15;
    const int wm = wave >> 2, wn = wave & 3;
    float* P = part + (size_t)kz * ROWS * D_MODEL;
#pragma unroll
    for (int ni = 0; ni < 4; ++ni) {
        int gc = col0 + wn * 64 + ni * 16 + l16;
#pragma unroll
        for (int mi = 0; mi < 8; ++mi)
#pragma unroll
            for (int r = 0; r < 4; ++r) {
                int gr = row0 + wm * 128 + mi * 16 + quad * 4 + r;
                P[(size_t)gr * D_MODEL + gc] = g.acc[mi][ni][r];
            }
    }
}

// out = part0 + part1  (float4 vectorized)
__global__ void reduce_out_kernel(const float* __restrict__ part,
                                  float* __restrict__ out) {
    int i = blockIdx.x * 256 + threadIdx.x;     // ROWS*D_MODEL/4 exactly
    float4 a = ((const float4*)part)[i];
    float4 b = ((const float4*)(part + (size_t)ROWS * D_MODEL))[i];
    ((float4*)out)[i] = make_float4(a.x + b.x, a.y + b.y, a.z + b.z, a.w + b.w);
}

// fp32 -> bf16 cast, 4 elems/thread
__global__ void cvt_bf16_kernel(const float* __restrict__ src,
                                bf16* __restrict__ dst, int n4) {
    int i = blockIdx.x * 256 + threadIdx.x;
    if (i >= n4) return;
    float4 v = ((const float4*)src)[i];
    dst[i * 4 + 0] = __float2bfloat16(v.x);
    dst[i * 4 + 1] = __float2bfloat16(v.y);
    dst[i * 4 + 2] = __float2bfloat16(v.z);
    dst[i * 4 + 3] = __float2bfloat16(v.w);
}

// Wt[c][r] = W[r][c], fp32 -> bf16.
__global__ __launch_bounds__(256) void transpose_cvt_kernel(const float* __restrict__ W,
                                                            bf16* __restrict__ Wt,
                                                            int R, int C, int Cpad) {
    __shared__ float tile[32][33];
    int c0 = blockIdx.x * 32, r0 = blockIdx.y * 32;
    int tx = threadIdx.x & 31, ty = threadIdx.x >> 5;
    for (int i = ty; i < 32; i += 8) {
        int r = r0 + i, c = c0 + tx;
        tile[i][tx] = (c < C) ? W[(size_t)r * C + c] : 0.f;
    }
    __syncthreads();
    for (int i = ty; i < 32; i += 8) {
        int c = c0 + i, r = r0 + tx;
        stf(&Wt[(size_t)c * R + r], tile[tx][i]);
    }
}

// conv_w[ch][k] fp32  ->  Wc[k][ch] bf16  (coalesced tap-major layout)
__global__ void prep_convw_kernel(const float* __restrict__ conv_w,
                                  bf16* __restrict__ Wc) {
    int i = blockIdx.x * 256 + threadIdx.x;     // CONV_CH*4 = 9216
    if (i >= CONV_CH * 4) return;
    int ch = i >> 2, k = i & 3;
    Wc[k * CONV_CH + ch] = __float2bfloat16(conv_w[ch * 4 + k]);
}

// ---------------------------------------------------------------------------
// Depthwise causal conv (k=4) + bias + SiLU.  One thread = 4 rows x 8 channels.
// ---------------------------------------------------------------------------
__global__ __launch_bounds__(256) void conv_silu_kernel(const bf16* __restrict__ R,
                                                        const bf16* __restrict__ Wc,
                                                        const float* __restrict__ conv_b,
                                                        bf16* __restrict__ xBC) {
    int idx = blockIdx.x * 256 + threadIdx.x;   // ROWS/4 * 288 exactly
    int rq = idx / 288;
    int g = idx - rq * 288;
    int ch0 = g * 8;
    int row0 = rq * 4;
    int l0 = row0 & (SEQ - 1);

    uint4 rv[7];
#pragma unroll
    for (int j = 0; j < 7; ++j) {
        int ls = l0 - 3 + j;
        rv[j] = (ls >= 0) ? *(const uint4*)&R[(size_t)(row0 - 3 + j) * RCOLS + ch0]
                          : make_uint4(0u, 0u, 0u, 0u);
    }
    uint4 wv[4];
#pragma unroll
    for (int k = 0; k < 4; ++k)
        wv[k] = *(const uint4*)&Wc[k * CONV_CH + ch0];
    float4 b0 = ((const float4*)conv_b)[ch0 / 4];
    float4 b1 = ((const float4*)conv_b)[ch0 / 4 + 1];
    const float bias[8] = {b0.x, b0.y, b0.z, b0.w, b1.x, b1.y, b1.z, b1.w};
    float wf[4][8];
#pragma unroll
    for (int k = 0; k < 4; ++k) {
        const unsigned* wp = (const unsigned*)&wv[k];
#pragma unroll
        for (int j2 = 0; j2 < 4; ++j2) {
            wf[k][2 * j2]     = bfbits2f((unsigned short)(wp[j2] & 0xffff));
            wf[k][2 * j2 + 1] = bfbits2f((unsigned short)(wp[j2] >> 16));
        }
    }
#pragma unroll
    for (int j = 0; j < 4; ++j) {
        float acc[8];
#pragma unroll
        for (int cc = 0; cc < 8; ++cc) acc[cc] = bias[cc];
#pragma unroll
        for (int k = 0; k < 4; ++k) {
            const unsigned* vp = (const unsigned*)&rv[j + k];
#pragma unroll
            for (int j2 = 0; j2 < 4; ++j2) {
                unsigned v = vp[j2];
                acc[2 * j2]     += wf[k][2 * j2]     * bfbits2f((unsigned short)(v & 0xffff));
                acc[2 * j2 + 1] += wf[k][2 * j2 + 1] * bfbits2f((unsigned short)(v >> 16));
            }
        }
        unsigned o[4];
#pragma unroll
        for (int j2 = 0; j2 < 4; ++j2)
            o[j2] = (unsigned)bfbits(siluf_(acc[2 * j2])) |
                    ((unsigned)bfbits(siluf_(acc[2 * j2 + 1])) << 16);
        *(uint4*)&xBC[(size_t)(row0 + j) * CONV_CH + ch0] = make_uint4(o[0], o[1], o[2], o[3]);
    }
}

// dt[row][h0..h0+7] = softplus(R[row][CONV_CH+h] + dt_bias[h]), vectorized.
__global__ void dt_kernel(const bf16* __restrict__ R,
                          const float* __restrict__ dt_bias,
                          float* __restrict__ dtb) {
    int i = blockIdx.x * 256 + threadIdx.x;         // ROWS*4 exactly
    int row = i >> 2, h0 = (i & 3) * 8;
    uint4 v = *(const uint4*)&R[(size_t)row * RCOLS + CONV_CH + h0];
    float4 bia0 = ((const float4*)dt_bias)[h0 / 4];
    float4 bia1 = ((const float4*)dt_bias)[h0 / 4 + 1];
    const unsigned vv[4] = {v.x, v.y, v.z, v.w};
    const float bb[8] = {bia0.x, bia0.y, bia0.z, bia0.w, bia1.x, bia1.y, bia1.z, bia1.w};
    float o[8];
#pragma unroll
    for (int j = 0; j < 4; ++j) {
        float a = bfbits2f((unsigned short)(vv[j] & 0xffff)) + bb[2*j];
        float c = bfbits2f((unsigned short)(vv[j] >> 16)) + bb[2*j+1];
        o[2*j]   = (a > 20.f) ? a : log1pf(expf(a));
        o[2*j+1] = (c > 20.f) ? c : log1pf(expf(c));
    }
    float* dp = &dtb[(size_t)row * NHEADS + h0];
    *(float4*)dp       = make_float4(o[0], o[1], o[2], o[3]);
    *(float4*)(dp + 4) = make_float4(o[4], o[5], o[6], o[7]);
}

// Per (b,c,h): inclusive cumsum of A[h]*dt over the 64-long chunk.
__global__ void acum_kernel(const float* __restrict__ dtb,
                            const float* __restrict__ A_log,
                            float* __restrict__ Acum) {
    int bch = blockIdx.x;
    int h = bch & 31;
    int bc = bch >> 5;
    int c = bc & 63, b = bc >> 6;
    int row0 = b * SEQ + c * CHUNK;
    __shared__ float sh[64];
    int l = threadIdx.x;
    float Ah = -expf(A_log[h]);
    sh[l] = Ah * dtb[(size_t)(row0 + l) * NHEADS + h];
    __syncthreads();
    float s = 0.f;
    for (int j = 0; j <= l; ++j) s += sh[j];
    Acum[(size_t)bch * 64 + l] = s;
}

// ---------------------------------------------------------------------------
// MFMA G-chunk: G[l][s] = sum_n C[l,n]*B[s,n].  One wave per (b,c).
// ---------------------------------------------------------------------------
__global__ __launch_bounds__(64) void gchunk_mfma_kernel(const bf16* __restrict__ xBC,
                                                         float* __restrict__ Gbuf) {
    int bc = blockIdx.x;
    int c = bc & 63, b = bc >> 6;
    int row0 = b * SEQ + c * CHUNK;
    int lane = threadIdx.x;
    int quad = lane >> 4, l16 = lane & 15;

    f32x4_t acc[4][4];
#pragma unroll
    for (int i = 0; i < 4; ++i)
#pragma unroll
        for (int j = 0; j < 4; ++j) acc[i][j] = (f32x4_t){0.f, 0.f, 0.f, 0.f};

#pragma unroll
    for (int ks = 0; ks < 4; ++ks) {
        bf16x8_t a[4], bb[4];
#pragma unroll
        for (int mi = 0; mi < 4; ++mi)
            a[mi] = *(const bf16x8_t*)&xBC[(size_t)(row0 + mi * 16 + l16) * CONV_CH +
                                           D_INNER + D_STATE + ks * 32 + quad * 8];
#pragma unroll
        for (int ni = 0; ni < 4; ++ni)
            bb[ni] = *(const bf16x8_t*)&xBC[(size_t)(row0 + ni * 16 + l16) * CONV_CH +
                                            D_INNER + ks * 32 + quad * 8];
#pragma unroll
        for (int mi = 0; mi < 4; ++mi)
#pragma unroll
            for (int ni = 0; ni < 4; ++ni)
                acc[mi][ni] = __builtin_amdgcn_mfma_f32_16x16x32_bf16(
                    a[mi], bb[ni], acc[mi][ni], 0, 0, 0);
    }
#pragma unroll
    for (int ni = 0; ni < 4; ++ni) {
        int s = ni * 16 + l16;
#pragma unroll
        for (int mi = 0; mi < 4; ++mi)
#pragma unroll
            for (int r = 0; r < 4; ++r) {
                int l = mi * 16 + quad * 4 + r;
                Gbuf[(size_t)bc * 4096 + l * 64 + s] = acc[mi][ni][r];
            }
    }
}

// ---------------------------------------------------------------------------
// MFMA chunk-states: S[p][n] = sum_l (x[l,p]*dt[l]*dec[l]) * B[l,n].
// ---------------------------------------------------------------------------
__global__ __launch_bounds__(256) void states_mfma_kernel(const bf16* __restrict__ xBC,
                                                          const float* __restrict__ dtb,
                                                          const float* __restrict__ Acum,
                                                          bf16* __restrict__ states) {
    __shared__ __align__(16) __bf16 BsT[128 * 72];      // [n][l], stride 72 (144 B)
    __shared__ __align__(16) __bf16 xdT[4][64 * 72];    // per-wave [p][l]
    __shared__ float dtdec[4][64];
    int bcq = blockIdx.x;                 // (b*64+c)*8 + hq
    int hq = bcq & 7, bc = bcq >> 3;
    int c = bc & 63, b = bc >> 6;
    int tid = threadIdx.x, wave = tid >> 6, lane = tid & 63;
    int h = hq * 4 + wave;
    int bch = bc * 32 + h;
    int row0 = b * SEQ + c * CHUNK;
    int quad = lane >> 4, l16 = lane & 15;

    {
        float alast = Acum[(size_t)bch * 64 + 63];
        float a = Acum[(size_t)bch * 64 + lane];
        dtdec[wave][lane] = dtb[(size_t)(row0 + lane) * NHEADS + h] * expf(alast - a);
    }
    __syncthreads();
    for (int it = 0; it < 16; ++it) {
        int i2 = tid + 256 * it;
        int l = i2 >> 6;
        int n0 = (i2 & 63) * 2;
        unsigned v = *(const unsigned*)&xBC[(size_t)(row0 + l) * CONV_CH + D_INNER + n0];
        *(unsigned short*)&BsT[(n0    ) * 72 + l] = (unsigned short)(v & 0xffff);
        *(unsigned short*)&BsT[(n0 + 1) * 72 + l] = (unsigned short)(v >> 16);
    }
    for (int it = 0; it < 32; ++it) {
        int l = 2 * it + (lane >> 5);
        int p0 = (lane & 31) * 2;
        unsigned v = *(const unsigned*)&xBC[(size_t)(row0 + l) * CONV_CH + h * 64 + p0];
        float f = dtdec[wave][l];
        xdT[wave][(p0    ) * 72 + l] = tobf(bfbits2f((unsigned short)(v & 0xffff)) * f);
        xdT[wave][(p0 + 1) * 72 + l] = tobf(bfbits2f((unsigned short)(v >> 16)) * f);
    }
    __syncthreads();

    f32x4_t acc[4][8];
#pragma unroll
    for (int i = 0; i < 4; ++i)
#pragma unroll
        for (int j = 0; j < 8; ++j) acc[i][j] = (f32x4_t){0.f, 0.f, 0.f, 0.f};
#pragma unroll
    for (int ks = 0; ks < 2; ++ks) {
        bf16x8_t a[4], bb[8];
#pragma unroll
        for (int mi = 0; mi < 4; ++mi)
            a[mi] = *(const bf16x8_t*)(&xdT[wave][(mi * 16 + l16) * 72 + ks * 32 + quad * 8]);
#pragma unroll
        for (int ni = 0; ni < 8; ++ni)
            bb[ni] = *(const bf16x8_t*)(&BsT[(ni * 16 + l16) * 72 + ks * 32 + quad * 8]);
#pragma unroll
        for (int mi = 0; mi < 4; ++mi)
#pragma unroll
            for (int ni = 0; ni < 8; ++ni)
                acc[mi][ni] = __builtin_amdgcn_mfma_f32_16x16x32_bf16(
                    a[mi], bb[ni], acc[mi][ni], 0, 0, 0);
    }
#pragma unroll
    for (int ni = 0; ni < 8; ++ni) {
        int n = ni * 16 + l16;
#pragma unroll
        for (int mi = 0; mi < 4; ++mi)
#pragma unroll
            for (int r = 0; r < 4; ++r) {
                int p = mi * 16 + quad * 4 + r;
                stf(&states[(size_t)bch * 8192 + p * 128 + n], acc[mi][ni][r]);
            }
    }
}

// Inter-chunk scan (in place), 4 states/thread, fp32 carry.
__global__ void scan_kernel(const float* __restrict__ Acum,
                            bf16* __restrict__ states) {
    int i = blockIdx.x * 256 + threadIdx.x;     // BATCH*NHEADS*2048 exactly
    int pn0 = (i & 2047) * 4;
    int bh = i >> 11;
    int h = bh & 31, b = bh >> 5;
    float carry[4] = {0.f, 0.f, 0.f, 0.f};
    for (int c = 0; c < NCHUNK; ++c) {
        int bch = (b * NCHUNK + c) * NHEADS + h;
        bf16* sp = &states[(size_t)bch * 8192 + pn0];
        uint2 v = *(const uint2*)sp;
        float s0 = bfbits2f((unsigned short)(v.x & 0xffff));
        float s1 = bfbits2f((unsigned short)(v.x >> 16));
        float s2 = bfbits2f((unsigned short)(v.y & 0xffff));
        float s3 = bfbits2f((unsigned short)(v.y >> 16));
        uint2 o;
        o.x = (unsigned)bfbits(carry[0]) | ((unsigned)bfbits(carry[1]) << 16);
        o.y = (unsigned)bfbits(carry[2]) | ((unsigned)bfbits(carry[3]) << 16);
        *(uint2*)sp = o;
        float dec = expf(Acum[(size_t)bch * 64 + 63]);
        carry[0] = carry[0] * dec + s0;
        carry[1] = carry[1] * dec + s1;
        carry[2] = carry[2] * dec + s2;
        carry[3] = carry[3] * dec + s3;
    }
}

// ---------------------------------------------------------------------------
// MFMA Y: Y[l][p] = sum_s M[l][s]*x[s][p] + sum_n (C[l][n]*sdo[l])*state[p][n]
//                  + D[h]*x[l][p].   One wave per (b,c,h).
// ---------------------------------------------------------------------------
__global__ __launch_bounds__(64) void y_mfma_kernel(const bf16* __restrict__ xBC,
                                                    const float* __restrict__ dtb,
                                                    const float* __restrict__ Acum,
                                                    const float* __restrict__ Gbuf,
                                                    const bf16* __restrict__ states,
                                                    const float* __restrict__ Dv,
                                                    bf16* __restrict__ y) {
    __shared__ __align__(16) __bf16 Mm[64 * 72];
    __shared__ __align__(16) __bf16 xsT[64 * 72];
    __shared__ float acs[64], dtss[64], sdos[64];
    int bch = blockIdx.x;
    int h = bch & 31, bc = bch >> 5;
    int c = bc & 63, b = bc >> 6;
    int row0 = b * SEQ + c * CHUNK;
    int lane = threadIdx.x;
    int quad = lane >> 4, l16 = lane & 15;

    {
        float a = Acum[(size_t)bch * 64 + lane];
        acs[lane] = a;
        sdos[lane] = expf(a);
        dtss[lane] = dtb[(size_t)(row0 + lane) * NHEADS + h];
    }
    __syncthreads();
    for (int l = 0; l < 64; ++l) {
        int s = lane;
        float d = acs[l] - acs[s];
        float g = (s <= l) ? Gbuf[(size_t)bc * 4096 + l * 64 + s] * dtss[s] : 0.f;
        float coef = g * expf((s <= l) ? d : 0.f);
        Mm[l * 72 + s] = tobf(coef);
    }
    for (int it = 0; it < 32; ++it) {
        int l = 2 * it + (lane >> 5);
        int p0 = (lane & 31) * 2;
        unsigned v = *(const unsigned*)&xBC[(size_t)(row0 + l) * CONV_CH + h * 64 + p0];
        *(unsigned short*)&xsT[(p0    ) * 72 + l] = (unsigned short)(v & 0xffff);
        *(unsigned short*)&xsT[(p0 + 1) * 72 + l] = (unsigned short)(v >> 16);
    }
    __syncthreads();

    f32x4_t acc[4][4];
#pragma unroll
    for (int i = 0; i < 4; ++i)
#pragma unroll
        for (int j = 0; j < 4; ++j) acc[i][j] = (f32x4_t){0.f, 0.f, 0.f, 0.f};

#pragma unroll
    for (int ks = 0; ks < 2; ++ks) {
        bf16x8_t a[4], bb[4];
#pragma unroll
        for (int mi = 0; mi < 4; ++mi)
            a[mi] = *(const bf16x8_t*)(&Mm[(mi * 16 + l16) * 72 + ks * 32 + quad * 8]);
#pragma unroll
        for (int ni = 0; ni < 4; ++ni)
            bb[ni] = *(const bf16x8_t*)(&xsT[(ni * 16 + l16) * 72 + ks * 32 + quad * 8]);
#pragma unroll
        for (int mi = 0; mi < 4; ++mi)
#pragma unroll
            for (int ni = 0; ni < 4; ++ni)
                acc[mi][ni] = __builtin_amdgcn_mfma_f32_16x16x32_bf16(
                    a[mi], bb[ni], acc[mi][ni], 0, 0, 0);
    }
    float sdo_mi[4];
#pragma unroll
    for (int mi = 0; mi < 4; ++mi) sdo_mi[mi] = sdos[mi * 16 + l16];
#pragma unroll
    for (int ks = 0; ks < 4; ++ks) {
        bf16x8_t a[4], bb[4];
#pragma unroll
        for (int mi = 0; mi < 4; ++mi) {
            const unsigned* cp = (const unsigned*)&xBC[(size_t)(row0 + mi * 16 + l16) * CONV_CH
                                                       + D_INNER + D_STATE + ks * 32 + quad * 8];
            float sc = sdo_mi[mi];
#pragma unroll
            for (int jj = 0; jj < 4; ++jj) {
                unsigned v = cp[jj];
                a[mi][2 * jj    ] = tobf(bfbits2f((unsigned short)(v & 0xffff)) * sc);
                a[mi][2 * jj + 1] = tobf(bfbits2f((unsigned short)(v >> 16)) * sc);
            }
        }
#pragma unroll
        for (int ni = 0; ni < 4; ++ni)
            bb[ni] = *(const bf16x8_t*)&states[(size_t)bch * 8192 + (ni * 16 + l16) * 128
                                               + ks * 32 + quad * 8];
#pragma unroll
        for (int mi = 0; mi < 4; ++mi)
#pragma unroll
            for (int ni = 0; ni < 4; ++ni)
                acc[mi][ni] = __builtin_amdgcn_mfma_f32_16x16x32_bf16(
                    a[mi], bb[ni], acc[mi][ni], 0, 0, 0);
    }
    float Dh = Dv[h];
#pragma unroll
    for (int ni = 0; ni < 4; ++ni) {
        int p = ni * 16 + l16;
#pragma unroll
        for (int mi = 0; mi < 4; ++mi)
#pragma unroll
            for (int r = 0; r < 4; ++r) {
                int l = mi * 16 + quad * 4 + r;
                float xv = bfbits2f(*(const unsigned short*)&xsT[p * 72 + l]);
                stf(&y[(size_t)(row0 + l) * D_INNER + h * 64 + p],
                    acc[mi][ni][r] + Dh * xv);
            }
    }
}

// Per row: v = y * silu(z); y = v * rsqrt(mean(v^2)+eps) * norm_w.
__global__ __launch_bounds__(256) void gate_norm_kernel(const bf16* __restrict__ Z,
                                                        const float* __restrict__ nw,
                                                        bf16* __restrict__ y) {
    int row = blockIdx.x;
    int tid = threadIdx.x;
    int col0 = tid * 8;
    uint4 zv = *(const uint4*)&Z[(size_t)row * D_INNER + col0];
    uint4 yv = *(const uint4*)&y[(size_t)row * D_INNER + col0];
    const unsigned zz[4] = {zv.x, zv.y, zv.z, zv.w};
    const unsigned yy[4] = {yv.x, yv.y, yv.z, yv.w};
    float vals[8];
    float local = 0.f;
#pragma unroll
    for (int j = 0; j < 4; ++j) {
        float z0 = bfbits2f((unsigned short)(zz[j] & 0xffff));
        float z1 = bfbits2f((unsigned short)(zz[j] >> 16));
        float y0 = bfbits2f((unsigned short)(yy[j] & 0xffff));
        float y1 = bfbits2f((unsigned short)(yy[j] >> 16));
        float v0 = y0 * siluf_(z0);
        float v1 = y1 * siluf_(z1);
        vals[2*j] = v0; vals[2*j+1] = v1;
        local += v0 * v0 + v1 * v1;
    }
#pragma unroll
    for (int off = 32; off; off >>= 1) local += __shfl_down(local, off, 64);
    __shared__ float wsum[4];
    if ((tid & 63) == 0) wsum[tid >> 6] = local;
    __syncthreads();
    float total = wsum[0] + wsum[1] + wsum[2] + wsum[3];
    float scale = rsqrtf(total / (float)D_INNER + EPS_RMS);
    float4 w0 = ((const float4*)nw)[col0 / 4];
    float4 w1 = ((const float4*)nw)[col0 / 4 + 1];
    const float ww[8] = {w0.x, w0.y, w0.z, w0.w, w1.x, w1.y, w1.z, w1.w};
    unsigned o[4];
#pragma unroll
    for (int j = 0; j < 4; ++j)
        o[j] = (unsigned)bfbits(vals[2*j] * scale * ww[2*j]) |
               ((unsigned)bfbits(vals[2*j+1] * scale * ww[2*j+1]) << 16);
    *(uint4*)&y[(size_t)row * D_INNER + col0] = make_uint4(o[0], o[1], o[2], o[3]);
}

// ---------------------------------------------------------------------------
extern "C" void kernel_launch(void* const* d_in, const int* in_sizes, int n_in,
                              void* d_out, int out_size, void* d_ws, size_t ws_size,
                              hipStream_t stream) {
    const float* u       = (const float*)d_in[0];
    const float* W_in    = (const float*)d_in[1];
    const float* conv_w  = (const float*)d_in[2];
    const float* conv_b  = (const float*)d_in[3];
    const float* dt_bias = (const float*)d_in[4];
    const float* A_log   = (const float*)d_in[5];
    const float* Dv      = (const float*)d_in[6];
    const float* norm_w  = (const float*)d_in[7];
    const float* W_out   = (const float*)d_in[8];
    float* out = (float*)d_out;

    const size_t sz_xBC    = (size_t)ROWS * CONV_CH * 2;
    const size_t sz_Z      = (size_t)ROWS * D_INNER * 2;
    const size_t sz_y      = (size_t)ROWS * D_INNER * 2;
    const size_t sz_states = (size_t)BATCH * NCHUNK * NHEADS * 8192 * 2;  // 67.1 MB
    const size_t sz_dtb    = (size_t)ROWS * NHEADS * 4;
    const size_t sz_Acum   = (size_t)BATCH * NCHUNK * NHEADS * 64 * 4;
    const size_t sz_Gbuf   = (size_t)BATCH * NCHUNK * 4096 * 4;
    const size_t sz_WinT   = (size_t)WINT_ROWS * D_MODEL * 2;
    const size_t sz_WoutT  = (size_t)D_MODEL * D_INNER * 2;
    const size_t sz_Wc     = (size_t)CONV_CH * 4 * 2;
    const size_t need = sz_xBC + sz_Z + sz_y + sz_states + sz_dtb + sz_Acum +
                        sz_Gbuf + sz_WinT + sz_WoutT + sz_Wc;
    if (ws_size < need) {
        hipMemsetAsync(d_out, 0, (size_t)out_size * sizeof(float), stream);
        return;
    }
    char* ws = (char*)d_ws;
    size_t off = 0;
    bf16*  xBC    = (bf16*) (ws + off); off += sz_xBC;
    bf16*  Z      = (bf16*) (ws + off); off += sz_Z;
    bf16*  y      = (bf16*) (ws + off); off += sz_y;
    bf16*  states = (bf16*) (ws + off); off += sz_states;
    float* dtb    = (float*)(ws + off); off += sz_dtb;
    float* Acum   = (float*)(ws + off); off += sz_Acum;
    float* Gbuf   = (float*)(ws + off); off += sz_Gbuf;
    bf16*  W_inT  = (bf16*) (ws + off); off += sz_WinT;
    bf16*  W_outT = (bf16*) (ws + off); off += sz_WoutT;
    bf16*  Wc     = (bf16*) (ws + off); off += sz_Wc;
    // Aliases of the states region (67.1 MB), all dead before their overwrite:
    //  - R (38.3 MB) + u_bf16 (16.8 MB): dead before states_mfma_kernel.
    //  - out_part (2 x 33.55 MB fp32 = 67.1 MB): written after gate_norm,
    //    when states is dead (last read: y_mfma_kernel).
    bf16*  R        = states;
    bf16*  u_bf16   = (bf16*)((char*)states + (size_t)ROWS * RCOLS * 2);
    float* out_part = (float*)states;

    // 0) prep
    cvt_bf16_kernel<<<(ROWS * D_MODEL / 4 + 255) / 256, 256, 0, stream>>>(
        u, u_bf16, ROWS * D_MODEL / 4);
    transpose_cvt_kernel<<<dim3(WINT_ROWS / 32, D_MODEL / 32), 256, 0, stream>>>(
        W_in, W_inT, D_MODEL, D_IN_PROJ, WINT_ROWS);
    transpose_cvt_kernel<<<dim3(D_MODEL / 32, D_INNER / 32), 256, 0, stream>>>(
        W_out, W_outT, D_INNER, D_MODEL, D_MODEL);
    prep_convw_kernel<<<(CONV_CH * 4 + 255) / 256, 256, 0, stream>>>(conv_w, Wc);
    // 1) fused Z|R GEMM: m201-geometry 256x256 core, 32x18 = 576 blocks
    gemm_zr_fused<<<dim3(ROWS / 256, WINT_ROWS / 256), 512, 0, stream>>>(
        u_bf16, W_inT, Z, R);
    // 2) conv + silu (4 rows/thread) ; dt
    conv_silu_kernel<<<ROWS / 4 * 288 / 256, 256, 0, stream>>>(R, Wc, conv_b, xBC);
    dt_kernel<<<ROWS * 4 / 256, 256, 0, stream>>>(R, dt_bias, dtb);
    // 3) per-chunk cumsum of A*dt
    acum_kernel<<<BATCH * NCHUNK * NHEADS, 64, 0, stream>>>(dtb, A_log, Acum);
    // 4) G = C @ B^T per (b,c)  (MFMA)
    gchunk_mfma_kernel<<<BATCH * NCHUNK, 64, 0, stream>>>(xBC, Gbuf);
    // 5) per-chunk states (MFMA; overwrites R/u_bf16 aliases — both dead)
    states_mfma_kernel<<<BATCH * NCHUNK * 8, 256, 0, stream>>>(xBC, dtb, Acum, states);
    // 6) inter-chunk scan (4 elems/thread)
    scan_kernel<<<BATCH * NHEADS * 2048 / 256, 256, 0, stream>>>(Acum, states);
    // 7+8) Y = diag + off + D*x  (MFMA, fused)
    y_mfma_kernel<<<BATCH * NCHUNK * NHEADS, 64, 0, stream>>>(
        xBC, dtb, Acum, Gbuf, states, Dv, y);
    // 9) gate + RMSNorm
    gate_norm_kernel<<<ROWS, 256, 0, stream>>>(Z, norm_w, y);
    // 10) out = y @ W_out, split-K=2 on the 256x256 core (partials overwrite
    //     dead states region), then reduce.
    gemm_out_splitk<<<dim3(ROWS / 256, D_MODEL / 256, 2), 512, 0, stream>>>(
        y, W_outT, out_part);
    reduce_out_kernel<<<ROWS * D_MODEL / 4 / 256, 256, 0, stream>>>(out_part, out);
}

// Round 4
// 415.008 us; speedup vs baseline: 1.0699x; 1.0699x over previous
//
#include <hip/hip_runtime.h>
#include <hip/hip_bf16.h>
#include <math.h>

#define D_MODEL   1024
#define D_STATE   128
#define HEADDIM   64
#define CHUNK     64
#define D_INNER   2048
#define NHEADS    32
#define D_IN_PROJ 4384   // 2*2048 + 2*128 + 32
#define CONV_CH   2304   // 2048 + 256
#define RCOLS     2336   // CONV_CH + NHEADS (xBC-raw + dt-raw columns)
#define WINT_ROWS 4480   // D_IN_PROJ padded so col-tile 34 stays in-bounds
#define BATCH     2
#define SEQ       4096
#define NCHUNK    64     // SEQ / CHUNK
#define ROWS      (BATCH*SEQ)   // 8192
#define EPS_RMS   1e-5f

typedef __hip_bfloat16 bf16;
typedef __bf16 bf16x8_t __attribute__((ext_vector_type(8)));
typedef float  f32x4_t  __attribute__((ext_vector_type(4)));

__device__ __forceinline__ float siluf_(float x){ return x/(1.f+expf(-x)); }
__device__ __forceinline__ float ldf(const float* p){ return *p; }
__device__ __forceinline__ float ldf(const bf16* p){ return __bfloat162float(*p); }
__device__ __forceinline__ void  stf(float* p, float v){ *p = v; }
__device__ __forceinline__ void  stf(bf16* p, float v){ *p = __float2bfloat16(v); }

__device__ __forceinline__ __bf16 tobf(float v){
    __hip_bfloat16 t = __float2bfloat16(v);
    return *reinterpret_cast<__bf16*>(&t);
}
__device__ __forceinline__ unsigned short bfbits(float v){
    __hip_bfloat16 t = __float2bfloat16(v);
    return *reinterpret_cast<unsigned short*>(&t);
}
__device__ __forceinline__ float bfbits2f(unsigned short u){
    union { unsigned u; float f; } cv; cv.u = ((unsigned)u) << 16; return cv.f;
}

// async global->LDS, 16 B per lane; LDS dest is wave-uniform base + lane*16.
__device__ __forceinline__ void async16(const void* g, void* l) {
    __builtin_amdgcn_global_load_lds(
        (const __attribute__((address_space(1))) unsigned int*)g,
        (__attribute__((address_space(3))) unsigned int*)l, 16, 0, 0);
}

// ---------------------------------------------------------------------------
// Shared MFMA K-loop body (m97 structure): 128x128 tile, BK=32, 4 waves,
// wave = 64x64 patch = 4x4 of 16x16x32 tiles.  (Round-0 proven: 99.5 us zr.)
//   a-frag = rows of M-by-K, b-frag = rows of N-by-K (lane: row=lane&15,
//   k=(lane>>4)*8+j);  D[m][n]: col n = lane&15, row m = (lane>>4)*4+reg.
// ---------------------------------------------------------------------------
struct GemmCore {
    f32x4_t acc[4][4];
    __device__ __forceinline__ void run(const bf16* __restrict__ A, int lda,
                                        const bf16* __restrict__ Bt, int ldb,
                                        int row0, int col0, int k0, int k1,
                                        __bf16* As, __bf16* Bs,
                                        int wave, int lane) {
        const int quad = lane >> 4, l16 = lane & 15;
        const int wr = (wave >> 1) * 64, wc = (wave & 1) * 64;
#pragma unroll
        for (int i = 0; i < 4; ++i)
#pragma unroll
            for (int j = 0; j < 4; ++j) acc[i][j] = (f32x4_t){0.f, 0.f, 0.f, 0.f};
        const int ca0 = wave * 2, ca1 = wave * 2 + 1;
        const int srow = lane >> 2, scol = (lane & 3) * 8;
        const bf16* Ag0 = A  + (size_t)(row0 + ca0 * 16 + srow) * lda + scol;
        const bf16* Ag1 = A  + (size_t)(row0 + ca1 * 16 + srow) * lda + scol;
        const bf16* Bg0 = Bt + (size_t)(col0 + ca0 * 16 + srow) * ldb + scol;
        const bf16* Bg1 = Bt + (size_t)(col0 + ca1 * 16 + srow) * ldb + scol;
        __bf16* Al0 = As + ca0 * 512;
        __bf16* Al1 = As + ca1 * 512;
        __bf16* Bl0 = Bs + ca0 * 512;
        __bf16* Bl1 = Bs + ca1 * 512;
        for (int kk = k0; kk < k1; kk += 32) {
            async16(Ag0 + kk, Al0);
            async16(Ag1 + kk, Al1);
            async16(Bg0 + kk, Bl0);
            async16(Bg1 + kk, Bl1);
            __syncthreads();
            bf16x8_t af[4], bfr[4];
#pragma unroll
            for (int mi = 0; mi < 4; ++mi)
                af[mi] = *(const bf16x8_t*)(As + (wr + mi * 16 + l16) * 32 + quad * 8);
#pragma unroll
            for (int ni = 0; ni < 4; ++ni)
                bfr[ni] = *(const bf16x8_t*)(Bs + (wc + ni * 16 + l16) * 32 + quad * 8);
#pragma unroll
            for (int mi = 0; mi < 4; ++mi)
#pragma unroll
                for (int ni = 0; ni < 4; ++ni)
                    acc[mi][ni] = __builtin_amdgcn_mfma_f32_16x16x32_bf16(
                        af[mi], bfr[ni], acc[mi][ni], 0, 0, 0);
            __syncthreads();
        }
    }
};

// Fused Z|R GEMM: one dispatch over all 35 col-tiles of W_inT.
// grid = (64 row-tiles, 35 col-tiles); consecutive blocks share the B tile.
__global__ __launch_bounds__(256) void gemm_zr_fused(const bf16* __restrict__ A,
                                                     const bf16* __restrict__ Bt,
                                                     bf16* __restrict__ Z,
                                                     bf16* __restrict__ R) {
    __shared__ __align__(16) __bf16 As[128 * 32];
    __shared__ __align__(16) __bf16 Bs[128 * 32];
    const int tid = threadIdx.x, wave = tid >> 6, lane = tid & 63;
    const int quad = lane >> 4, l16 = lane & 15;
    const int row0 = blockIdx.x * 128;
    const int ct   = blockIdx.y;
    GemmCore g;
    g.run(A, D_MODEL, Bt, D_MODEL, row0, ct * 128, 0, D_MODEL, As, Bs, wave, lane);

    bf16* Cp; int ldc_, cl0, ncols;
    if (ct < 16) { Cp = Z; ldc_ = D_INNER; cl0 = ct * 128;          ncols = D_INNER; }
    else         { Cp = R; ldc_ = RCOLS;   cl0 = ct * 128 - D_INNER; ncols = RCOLS; }
    const int wr = (wave >> 1) * 64, wc = (wave & 1) * 64;
#pragma unroll
    for (int ni = 0; ni < 4; ++ni) {
        int gc = cl0 + wc + ni * 16 + l16;
        if (gc >= ncols) continue;
#pragma unroll
        for (int mi = 0; mi < 4; ++mi)
#pragma unroll
            for (int r = 0; r < 4; ++r) {
                int gr = row0 + wr + mi * 16 + quad * 4 + r;
                stf(&Cp[(size_t)gr * ldc_ + gc], g.acc[mi][ni][r]);
            }
    }
}

// Out GEMM, full K=2048, fp32 direct to out (no split-K partial round-trip).
// grid (64, 8) = 512 blocks.
__global__ __launch_bounds__(256) void gemm_out_kernel(const bf16* __restrict__ A,
                                                       const bf16* __restrict__ Bt,
                                                       float* __restrict__ out) {
    __shared__ __align__(16) __bf16 As[128 * 32];
    __shared__ __align__(16) __bf16 Bs[128 * 32];
    const int tid = threadIdx.x, wave = tid >> 6, lane = tid & 63;
    const int quad = lane >> 4, l16 = lane & 15;
    const int row0 = blockIdx.x * 128;
    const int col0 = blockIdx.y * 128;
    GemmCore g;
    g.run(A, D_INNER, Bt, D_INNER, row0, col0, 0, D_INNER, As, Bs, wave, lane);
    const int wr = (wave >> 1) * 64, wc = (wave & 1) * 64;
#pragma unroll
    for (int ni = 0; ni < 4; ++ni) {
        int gc = col0 + wc + ni * 16 + l16;
#pragma unroll
        for (int mi = 0; mi < 4; ++mi)
#pragma unroll
            for (int r = 0; r < 4; ++r) {
                int gr = row0 + wr + mi * 16 + quad * 4 + r;
                out[(size_t)gr * D_MODEL + gc] = g.acc[mi][ni][r];
            }
    }
}

// fp32 -> bf16 cast, 4 elems/thread
__global__ void cvt_bf16_kernel(const float* __restrict__ src,
                                bf16* __restrict__ dst, int n4) {
    int i = blockIdx.x * 256 + threadIdx.x;
    if (i >= n4) return;
    float4 v = ((const float4*)src)[i];
    dst[i * 4 + 0] = __float2bfloat16(v.x);
    dst[i * 4 + 1] = __float2bfloat16(v.y);
    dst[i * 4 + 2] = __float2bfloat16(v.z);
    dst[i * 4 + 3] = __float2bfloat16(v.w);
}

// Wt[c][r] = W[r][c], fp32 -> bf16.
__global__ __launch_bounds__(256) void transpose_cvt_kernel(const float* __restrict__ W,
                                                            bf16* __restrict__ Wt,
                                                            int R, int C, int Cpad) {
    __shared__ float tile[32][33];
    int c0 = blockIdx.x * 32, r0 = blockIdx.y * 32;
    int tx = threadIdx.x & 31, ty = threadIdx.x >> 5;
    for (int i = ty; i < 32; i += 8) {
        int r = r0 + i, c = c0 + tx;
        tile[i][tx] = (c < C) ? W[(size_t)r * C + c] : 0.f;
    }
    __syncthreads();
    for (int i = ty; i < 32; i += 8) {
        int c = c0 + i, r = r0 + tx;
        stf(&Wt[(size_t)c * R + r], tile[tx][i]);
    }
}

// conv_w[ch][k] fp32  ->  Wc[k][ch] bf16  (coalesced tap-major layout)
__global__ void prep_convw_kernel(const float* __restrict__ conv_w,
                                  bf16* __restrict__ Wc) {
    int i = blockIdx.x * 256 + threadIdx.x;     // CONV_CH*4 = 9216
    if (i >= CONV_CH * 4) return;
    int ch = i >> 2, k = i & 3;
    Wc[k * CONV_CH + ch] = __float2bfloat16(conv_w[ch * 4 + k]);
}

// ---------------------------------------------------------------------------
// Depthwise causal conv (k=4) + bias + SiLU.  One thread = 4 rows x 8 channels.
// ---------------------------------------------------------------------------
__global__ __launch_bounds__(256) void conv_silu_kernel(const bf16* __restrict__ R,
                                                        const bf16* __restrict__ Wc,
                                                        const float* __restrict__ conv_b,
                                                        bf16* __restrict__ xBC) {
    int idx = blockIdx.x * 256 + threadIdx.x;   // ROWS/4 * 288 exactly
    int rq = idx / 288;
    int g = idx - rq * 288;
    int ch0 = g * 8;
    int row0 = rq * 4;
    int l0 = row0 & (SEQ - 1);

    uint4 rv[7];
#pragma unroll
    for (int j = 0; j < 7; ++j) {
        int ls = l0 - 3 + j;
        rv[j] = (ls >= 0) ? *(const uint4*)&R[(size_t)(row0 - 3 + j) * RCOLS + ch0]
                          : make_uint4(0u, 0u, 0u, 0u);
    }
    uint4 wv[4];
#pragma unroll
    for (int k = 0; k < 4; ++k)
        wv[k] = *(const uint4*)&Wc[k * CONV_CH + ch0];
    float4 b0 = ((const float4*)conv_b)[ch0 / 4];
    float4 b1 = ((const float4*)conv_b)[ch0 / 4 + 1];
    const float bias[8] = {b0.x, b0.y, b0.z, b0.w, b1.x, b1.y, b1.z, b1.w};
    float wf[4][8];
#pragma unroll
    for (int k = 0; k < 4; ++k) {
        const unsigned* wp = (const unsigned*)&wv[k];
#pragma unroll
        for (int j2 = 0; j2 < 4; ++j2) {
            wf[k][2 * j2]     = bfbits2f((unsigned short)(wp[j2] & 0xffff));
            wf[k][2 * j2 + 1] = bfbits2f((unsigned short)(wp[j2] >> 16));
        }
    }
#pragma unroll
    for (int j = 0; j < 4; ++j) {
        float acc[8];
#pragma unroll
        for (int cc = 0; cc < 8; ++cc) acc[cc] = bias[cc];
#pragma unroll
        for (int k = 0; k < 4; ++k) {
            const unsigned* vp = (const unsigned*)&rv[j + k];
#pragma unroll
            for (int j2 = 0; j2 < 4; ++j2) {
                unsigned v = vp[j2];
                acc[2 * j2]     += wf[k][2 * j2]     * bfbits2f((unsigned short)(v & 0xffff));
                acc[2 * j2 + 1] += wf[k][2 * j2 + 1] * bfbits2f((unsigned short)(v >> 16));
            }
        }
        unsigned o[4];
#pragma unroll
        for (int j2 = 0; j2 < 4; ++j2)
            o[j2] = (unsigned)bfbits(siluf_(acc[2 * j2])) |
                    ((unsigned)bfbits(siluf_(acc[2 * j2 + 1])) << 16);
        *(uint4*)&xBC[(size_t)(row0 + j) * CONV_CH + ch0] = make_uint4(o[0], o[1], o[2], o[3]);
    }
}

// dt[row][h0..h0+7] = softplus(R[row][CONV_CH+h] + dt_bias[h]), vectorized.
__global__ void dt_kernel(const bf16* __restrict__ R,
                          const float* __restrict__ dt_bias,
                          float* __restrict__ dtb) {
    int i = blockIdx.x * 256 + threadIdx.x;         // ROWS*4 exactly
    int row = i >> 2, h0 = (i & 3) * 8;
    uint4 v = *(const uint4*)&R[(size_t)row * RCOLS + CONV_CH + h0];
    float4 bia0 = ((const float4*)dt_bias)[h0 / 4];
    float4 bia1 = ((const float4*)dt_bias)[h0 / 4 + 1];
    const unsigned vv[4] = {v.x, v.y, v.z, v.w};
    const float bb[8] = {bia0.x, bia0.y, bia0.z, bia0.w, bia1.x, bia1.y, bia1.z, bia1.w};
    float o[8];
#pragma unroll
    for (int j = 0; j < 4; ++j) {
        float a = bfbits2f((unsigned short)(vv[j] & 0xffff)) + bb[2*j];
        float c = bfbits2f((unsigned short)(vv[j] >> 16)) + bb[2*j+1];
        o[2*j]   = (a > 20.f) ? a : log1pf(expf(a));
        o[2*j+1] = (c > 20.f) ? c : log1pf(expf(c));
    }
    float* dp = &dtb[(size_t)row * NHEADS + h0];
    *(float4*)dp       = make_float4(o[0], o[1], o[2], o[3]);
    *(float4*)(dp + 4) = make_float4(o[4], o[5], o[6], o[7]);
}

// Per (b,c,h): inclusive cumsum of A[h]*dt over the 64-long chunk.
__global__ void acum_kernel(const float* __restrict__ dtb,
                            const float* __restrict__ A_log,
                            float* __restrict__ Acum) {
    int bch = blockIdx.x;
    int h = bch & 31;
    int bc = bch >> 5;
    int c = bc & 63, b = bc >> 6;
    int row0 = b * SEQ + c * CHUNK;
    __shared__ float sh[64];
    int l = threadIdx.x;
    float Ah = -expf(A_log[h]);
    sh[l] = Ah * dtb[(size_t)(row0 + l) * NHEADS + h];
    __syncthreads();
    float s = 0.f;
    for (int j = 0; j <= l; ++j) s += sh[j];
    Acum[(size_t)bch * 64 + l] = s;
}

// ---------------------------------------------------------------------------
// MFMA chunk-states: S[p][n] = sum_l (x[l,p]*dt[l]*dec[l]) * B[l,n].
// ---------------------------------------------------------------------------
__global__ __launch_bounds__(256) void states_mfma_kernel(const bf16* __restrict__ xBC,
                                                          const float* __restrict__ dtb,
                                                          const float* __restrict__ Acum,
                                                          bf16* __restrict__ states) {
    __shared__ __align__(16) __bf16 BsT[128 * 72];      // [n][l], stride 72 (144 B)
    __shared__ __align__(16) __bf16 xdT[4][64 * 72];    // per-wave [p][l]
    __shared__ float dtdec[4][64];
    int bcq = blockIdx.x;                 // (b*64+c)*8 + hq
    int hq = bcq & 7, bc = bcq >> 3;
    int c = bc & 63, b = bc >> 6;
    int tid = threadIdx.x, wave = tid >> 6, lane = tid & 63;
    int h = hq * 4 + wave;
    int bch = bc * 32 + h;
    int row0 = b * SEQ + c * CHUNK;
    int quad = lane >> 4, l16 = lane & 15;

    {
        float alast = Acum[(size_t)bch * 64 + 63];
        float a = Acum[(size_t)bch * 64 + lane];
        dtdec[wave][lane] = dtb[(size_t)(row0 + lane) * NHEADS + h] * expf(alast - a);
    }
    __syncthreads();
    for (int it = 0; it < 16; ++it) {
        int i2 = tid + 256 * it;
        int l = i2 >> 6;
        int n0 = (i2 & 63) * 2;
        unsigned v = *(const unsigned*)&xBC[(size_t)(row0 + l) * CONV_CH + D_INNER + n0];
        *(unsigned short*)&BsT[(n0    ) * 72 + l] = (unsigned short)(v & 0xffff);
        *(unsigned short*)&BsT[(n0 + 1) * 72 + l] = (unsigned short)(v >> 16);
    }
    for (int it = 0; it < 32; ++it) {
        int l = 2 * it + (lane >> 5);
        int p0 = (lane & 31) * 2;
        unsigned v = *(const unsigned*)&xBC[(size_t)(row0 + l) * CONV_CH + h * 64 + p0];
        float f = dtdec[wave][l];
        xdT[wave][(p0    ) * 72 + l] = tobf(bfbits2f((unsigned short)(v & 0xffff)) * f);
        xdT[wave][(p0 + 1) * 72 + l] = tobf(bfbits2f((unsigned short)(v >> 16)) * f);
    }
    __syncthreads();

    f32x4_t acc[4][8];
#pragma unroll
    for (int i = 0; i < 4; ++i)
#pragma unroll
        for (int j = 0; j < 8; ++j) acc[i][j] = (f32x4_t){0.f, 0.f, 0.f, 0.f};
#pragma unroll
    for (int ks = 0; ks < 2; ++ks) {
        bf16x8_t a[4], bb[8];
#pragma unroll
        for (int mi = 0; mi < 4; ++mi)
            a[mi] = *(const bf16x8_t*)(&xdT[wave][(mi * 16 + l16) * 72 + ks * 32 + quad * 8]);
#pragma unroll
        for (int ni = 0; ni < 8; ++ni)
            bb[ni] = *(const bf16x8_t*)(&BsT[(ni * 16 + l16) * 72 + ks * 32 + quad * 8]);
#pragma unroll
        for (int mi = 0; mi < 4; ++mi)
#pragma unroll
            for (int ni = 0; ni < 8; ++ni)
                acc[mi][ni] = __builtin_amdgcn_mfma_f32_16x16x32_bf16(
                    a[mi], bb[ni], acc[mi][ni], 0, 0, 0);
    }
#pragma unroll
    for (int ni = 0; ni < 8; ++ni) {
        int n = ni * 16 + l16;
#pragma unroll
        for (int mi = 0; mi < 4; ++mi)
#pragma unroll
            for (int r = 0; r < 4; ++r) {
                int p = mi * 16 + quad * 4 + r;
                stf(&states[(size_t)bch * 8192 + p * 128 + n], acc[mi][ni][r]);
            }
    }
}

// Inter-chunk scan (in place), 4 states/thread, fp32 carry.
__global__ void scan_kernel(const float* __restrict__ Acum,
                            bf16* __restrict__ states) {
    int i = blockIdx.x * 256 + threadIdx.x;     // BATCH*NHEADS*2048 exactly
    int pn0 = (i & 2047) * 4;
    int bh = i >> 11;
    int h = bh & 31, b = bh >> 5;
    float carry[4] = {0.f, 0.f, 0.f, 0.f};
    for (int c = 0; c < NCHUNK; ++c) {
        int bch = (b * NCHUNK + c) * NHEADS + h;
        bf16* sp = &states[(size_t)bch * 8192 + pn0];
        uint2 v = *(const uint2*)sp;
        float s0 = bfbits2f((unsigned short)(v.x & 0xffff));
        float s1 = bfbits2f((unsigned short)(v.x >> 16));
        float s2 = bfbits2f((unsigned short)(v.y & 0xffff));
        float s3 = bfbits2f((unsigned short)(v.y >> 16));
        uint2 o;
        o.x = (unsigned)bfbits(carry[0]) | ((unsigned)bfbits(carry[1]) << 16);
        o.y = (unsigned)bfbits(carry[2]) | ((unsigned)bfbits(carry[3]) << 16);
        *(uint2*)sp = o;
        float dec = expf(Acum[(size_t)bch * 64 + 63]);
        carry[0] = carry[0] * dec + s0;
        carry[1] = carry[1] * dec + s1;
        carry[2] = carry[2] * dec + s2;
        carry[3] = carry[3] * dec + s3;
    }
}

// ---------------------------------------------------------------------------
// MFMA Y (gchunk FUSED): per (b,c,h) one wave.
//   Phase A: G[l][s] = sum_n C[l,n]*B[s,n] via MFMA (lower-tri tiles only),
//            then Mm[l][s] = mask(s<=l)*G*dt[s]*exp(acs[l]-acs[s]) built
//            register-parallel from the accumulator (no Gbuf, no serial loop).
//   Phase 1: Y_diag = Mm @ x  ;  Phase 2: Y_off = (C*sdo) @ states^T
//   Epilogue: + D[h]*x.
// ---------------------------------------------------------------------------
__global__ __launch_bounds__(64) void y_mfma_kernel(const bf16* __restrict__ xBC,
                                                    const float* __restrict__ dtb,
                                                    const float* __restrict__ Acum,
                                                    const bf16* __restrict__ states,
                                                    const float* __restrict__ Dv,
                                                    bf16* __restrict__ y) {
    __shared__ __align__(16) __bf16 Mm[64 * 72];
    __shared__ __align__(16) __bf16 xsT[64 * 72];
    __shared__ float acs[64], dtss[64], sdos[64];
    int bch = blockIdx.x;
    int h = bch & 31, bc = bch >> 5;
    int c = bc & 63, b = bc >> 6;
    int row0 = b * SEQ + c * CHUNK;
    int lane = threadIdx.x;
    int quad = lane >> 4, l16 = lane & 15;

    {
        float a = Acum[(size_t)bch * 64 + lane];
        acs[lane] = a;
        sdos[lane] = expf(a);
        dtss[lane] = dtb[(size_t)(row0 + lane) * NHEADS + h];
    }
    // x transpose into LDS (independent of acs)
    for (int it = 0; it < 32; ++it) {
        int l = 2 * it + (lane >> 5);
        int p0 = (lane & 31) * 2;
        unsigned v = *(const unsigned*)&xBC[(size_t)(row0 + l) * CONV_CH + h * 64 + p0];
        *(unsigned short*)&xsT[(p0    ) * 72 + l] = (unsigned short)(v & 0xffff);
        *(unsigned short*)&xsT[(p0 + 1) * 72 + l] = (unsigned short)(v >> 16);
    }
    __syncthreads();

    // ---- Phase A: G via MFMA (only mi >= ni tiles; upper tiles are masked)
    f32x4_t gacc[4][4];
#pragma unroll
    for (int i = 0; i < 4; ++i)
#pragma unroll
        for (int j = 0; j < 4; ++j) gacc[i][j] = (f32x4_t){0.f, 0.f, 0.f, 0.f};
#pragma unroll
    for (int ks = 0; ks < 4; ++ks) {
        bf16x8_t a[4], bb[4];
#pragma unroll
        for (int mi = 0; mi < 4; ++mi)
            a[mi] = *(const bf16x8_t*)&xBC[(size_t)(row0 + mi * 16 + l16) * CONV_CH +
                                           D_INNER + D_STATE + ks * 32 + quad * 8];
#pragma unroll
        for (int ni = 0; ni < 4; ++ni)
            bb[ni] = *(const bf16x8_t*)&xBC[(size_t)(row0 + ni * 16 + l16) * CONV_CH +
                                            D_INNER + ks * 32 + quad * 8];
#pragma unroll
        for (int mi = 0; mi < 4; ++mi)
#pragma unroll
            for (int ni = 0; ni <= mi; ++ni)
                gacc[mi][ni] = __builtin_amdgcn_mfma_f32_16x16x32_bf16(
                    a[mi], bb[ni], gacc[mi][ni], 0, 0, 0);
    }
    // Build Mm from gacc: l = mi*16+quad*4+r, s = ni*16+l16.
#pragma unroll
    for (int ni = 0; ni < 4; ++ni) {
        int s = ni * 16 + l16;
        float ds = dtss[s], as = acs[s];
#pragma unroll
        for (int mi = 0; mi < 4; ++mi)
#pragma unroll
            for (int r = 0; r < 4; ++r) {
                int l = mi * 16 + quad * 4 + r;
                float coef = (s <= l) ? gacc[mi][ni][r] * ds * expf(acs[l] - as) : 0.f;
                Mm[l * 72 + s] = tobf(coef);
            }
    }
    __syncthreads();

    f32x4_t acc[4][4];
#pragma unroll
    for (int i = 0; i < 4; ++i)
#pragma unroll
        for (int j = 0; j < 4; ++j) acc[i][j] = (f32x4_t){0.f, 0.f, 0.f, 0.f};

    // ---- Phase 1: Y_diag = Mm @ x
#pragma unroll
    for (int ks = 0; ks < 2; ++ks) {
        bf16x8_t a[4], bb[4];
#pragma unroll
        for (int mi = 0; mi < 4; ++mi)
            a[mi] = *(const bf16x8_t*)(&Mm[(mi * 16 + l16) * 72 + ks * 32 + quad * 8]);
#pragma unroll
        for (int ni = 0; ni < 4; ++ni)
            bb[ni] = *(const bf16x8_t*)(&xsT[(ni * 16 + l16) * 72 + ks * 32 + quad * 8]);
#pragma unroll
        for (int mi = 0; mi < 4; ++mi)
#pragma unroll
            for (int ni = 0; ni < 4; ++ni)
                acc[mi][ni] = __builtin_amdgcn_mfma_f32_16x16x32_bf16(
                    a[mi], bb[ni], acc[mi][ni], 0, 0, 0);
    }
    // ---- Phase 2: Y_off = (C*sdo) @ states^T
    float sdo_mi[4];
#pragma unroll
    for (int mi = 0; mi < 4; ++mi) sdo_mi[mi] = sdos[mi * 16 + l16];
#pragma unroll
    for (int ks = 0; ks < 4; ++ks) {
        bf16x8_t a[4], bb[4];
#pragma unroll
        for (int mi = 0; mi < 4; ++mi) {
            const unsigned* cp = (const unsigned*)&xBC[(size_t)(row0 + mi * 16 + l16) * CONV_CH
                                                       + D_INNER + D_STATE + ks * 32 + quad * 8];
            float sc = sdo_mi[mi];
#pragma unroll
            for (int jj = 0; jj < 4; ++jj) {
                unsigned v = cp[jj];
                a[mi][2 * jj    ] = tobf(bfbits2f((unsigned short)(v & 0xffff)) * sc);
                a[mi][2 * jj + 1] = tobf(bfbits2f((unsigned short)(v >> 16)) * sc);
            }
        }
#pragma unroll
        for (int ni = 0; ni < 4; ++ni)
            bb[ni] = *(const bf16x8_t*)&states[(size_t)bch * 8192 + (ni * 16 + l16) * 128
                                               + ks * 32 + quad * 8];
#pragma unroll
        for (int mi = 0; mi < 4; ++mi)
#pragma unroll
            for (int ni = 0; ni < 4; ++ni)
                acc[mi][ni] = __builtin_amdgcn_mfma_f32_16x16x32_bf16(
                    a[mi], bb[ni], acc[mi][ni], 0, 0, 0);
    }
    float Dh = Dv[h];
#pragma unroll
    for (int ni = 0; ni < 4; ++ni) {
        int p = ni * 16 + l16;
#pragma unroll
        for (int mi = 0; mi < 4; ++mi)
#pragma unroll
            for (int r = 0; r < 4; ++r) {
                int l = mi * 16 + quad * 4 + r;
                float xv = bfbits2f(*(const unsigned short*)&xsT[p * 72 + l]);
                stf(&y[(size_t)(row0 + l) * D_INNER + h * 64 + p],
                    acc[mi][ni][r] + Dh * xv);
            }
    }
}

// Per row: v = y * silu(z); y = v * rsqrt(mean(v^2)+eps) * norm_w.
__global__ __launch_bounds__(256) void gate_norm_kernel(const bf16* __restrict__ Z,
                                                        const float* __restrict__ nw,
                                                        bf16* __restrict__ y) {
    int row = blockIdx.x;
    int tid = threadIdx.x;
    int col0 = tid * 8;
    uint4 zv = *(const uint4*)&Z[(size_t)row * D_INNER + col0];
    uint4 yv = *(const uint4*)&y[(size_t)row * D_INNER + col0];
    const unsigned zz[4] = {zv.x, zv.y, zv.z, zv.w};
    const unsigned yy[4] = {yv.x, yv.y, yv.z, yv.w};
    float vals[8];
    float local = 0.f;
#pragma unroll
    for (int j = 0; j < 4; ++j) {
        float z0 = bfbits2f((unsigned short)(zz[j] & 0xffff));
        float z1 = bfbits2f((unsigned short)(zz[j] >> 16));
        float y0 = bfbits2f((unsigned short)(yy[j] & 0xffff));
        float y1 = bfbits2f((unsigned short)(yy[j] >> 16));
        float v0 = y0 * siluf_(z0);
        float v1 = y1 * siluf_(z1);
        vals[2*j] = v0; vals[2*j+1] = v1;
        local += v0 * v0 + v1 * v1;
    }
#pragma unroll
    for (int off = 32; off; off >>= 1) local += __shfl_down(local, off, 64);
    __shared__ float wsum[4];
    if ((tid & 63) == 0) wsum[tid >> 6] = local;
    __syncthreads();
    float total = wsum[0] + wsum[1] + wsum[2] + wsum[3];
    float scale = rsqrtf(total / (float)D_INNER + EPS_RMS);
    float4 w0 = ((const float4*)nw)[col0 / 4];
    float4 w1 = ((const float4*)nw)[col0 / 4 + 1];
    const float ww[8] = {w0.x, w0.y, w0.z, w0.w, w1.x, w1.y, w1.z, w1.w};
    unsigned o[4];
#pragma unroll
    for (int j = 0; j < 4; ++j)
        o[j] = (unsigned)bfbits(vals[2*j] * scale * ww[2*j]) |
               ((unsigned)bfbits(vals[2*j+1] * scale * ww[2*j+1]) << 16);
    *(uint4*)&y[(size_t)row * D_INNER + col0] = make_uint4(o[0], o[1], o[2], o[3]);
}

// ---------------------------------------------------------------------------
extern "C" void kernel_launch(void* const* d_in, const int* in_sizes, int n_in,
                              void* d_out, int out_size, void* d_ws, size_t ws_size,
                              hipStream_t stream) {
    const float* u       = (const float*)d_in[0];
    const float* W_in    = (const float*)d_in[1];
    const float* conv_w  = (const float*)d_in[2];
    const float* conv_b  = (const float*)d_in[3];
    const float* dt_bias = (const float*)d_in[4];
    const float* A_log   = (const float*)d_in[5];
    const float* Dv      = (const float*)d_in[6];
    const float* norm_w  = (const float*)d_in[7];
    const float* W_out   = (const float*)d_in[8];
    float* out = (float*)d_out;

    const size_t sz_xBC    = (size_t)ROWS * CONV_CH * 2;
    const size_t sz_Z      = (size_t)ROWS * D_INNER * 2;
    const size_t sz_y      = (size_t)ROWS * D_INNER * 2;
    const size_t sz_states = (size_t)BATCH * NCHUNK * NHEADS * 8192 * 2;  // 67.1 MB
    const size_t sz_dtb    = (size_t)ROWS * NHEADS * 4;
    const size_t sz_Acum   = (size_t)BATCH * NCHUNK * NHEADS * 64 * 4;
    const size_t sz_WinT   = (size_t)WINT_ROWS * D_MODEL * 2;
    const size_t sz_WoutT  = (size_t)D_MODEL * D_INNER * 2;
    const size_t sz_Wc     = (size_t)CONV_CH * 4 * 2;
    const size_t need = sz_xBC + sz_Z + sz_y + sz_states + sz_dtb + sz_Acum +
                        sz_WinT + sz_WoutT + sz_Wc;
    if (ws_size < need) {
        hipMemsetAsync(d_out, 0, (size_t)out_size * sizeof(float), stream);
        return;
    }
    char* ws = (char*)d_ws;
    size_t off = 0;
    bf16*  xBC    = (bf16*) (ws + off); off += sz_xBC;
    bf16*  Z      = (bf16*) (ws + off); off += sz_Z;
    bf16*  y      = (bf16*) (ws + off); off += sz_y;
    bf16*  states = (bf16*) (ws + off); off += sz_states;
    float* dtb    = (float*)(ws + off); off += sz_dtb;
    float* Acum   = (float*)(ws + off); off += sz_Acum;
    bf16*  W_inT  = (bf16*) (ws + off); off += sz_WinT;
    bf16*  W_outT = (bf16*) (ws + off); off += sz_WoutT;
    bf16*  Wc     = (bf16*) (ws + off); off += sz_Wc;
    // Aliases of the states region (67.1 MB), dead before their overwrite:
    //  - R (38.3 MB) + u_bf16 (16.8 MB): dead before states_mfma_kernel.
    bf16*  R        = states;
    bf16*  u_bf16   = (bf16*)((char*)states + (size_t)ROWS * RCOLS * 2);

    // 0) prep
    cvt_bf16_kernel<<<(ROWS * D_MODEL / 4 + 255) / 256, 256, 0, stream>>>(
        u, u_bf16, ROWS * D_MODEL / 4);
    transpose_cvt_kernel<<<dim3(WINT_ROWS / 32, D_MODEL / 32), 256, 0, stream>>>(
        W_in, W_inT, D_MODEL, D_IN_PROJ, WINT_ROWS);
    transpose_cvt_kernel<<<dim3(D_MODEL / 32, D_INNER / 32), 256, 0, stream>>>(
        W_out, W_outT, D_INNER, D_MODEL, D_MODEL);
    prep_convw_kernel<<<(CONV_CH * 4 + 255) / 256, 256, 0, stream>>>(conv_w, Wc);
    // 1) fused Z|R GEMM: round-0 proven core, 64x35 = 2240 blocks
    gemm_zr_fused<<<dim3(ROWS / 128, 35), 256, 0, stream>>>(u_bf16, W_inT, Z, R);
    // 2) conv + silu (4 rows/thread) ; dt
    conv_silu_kernel<<<ROWS / 4 * 288 / 256, 256, 0, stream>>>(R, Wc, conv_b, xBC);
    dt_kernel<<<ROWS * 4 / 256, 256, 0, stream>>>(R, dt_bias, dtb);
    // 3) per-chunk cumsum of A*dt
    acum_kernel<<<BATCH * NCHUNK * NHEADS, 64, 0, stream>>>(dtb, A_log, Acum);
    // 4) per-chunk states (MFMA; overwrites R/u_bf16 aliases — both dead)
    states_mfma_kernel<<<BATCH * NCHUNK * 8, 256, 0, stream>>>(xBC, dtb, Acum, states);
    // 5) inter-chunk scan (4 elems/thread)
    scan_kernel<<<BATCH * NHEADS * 2048 / 256, 256, 0, stream>>>(Acum, states);
    // 6) Y = diag + off + D*x  (MFMA; G computed in-block — gchunk fused away)
    y_mfma_kernel<<<BATCH * NCHUNK * NHEADS, 64, 0, stream>>>(
        xBC, dtb, Acum, states, Dv, y);
    // 7) gate + RMSNorm
    gate_norm_kernel<<<ROWS, 256, 0, stream>>>(Z, norm_w, y);
    // 8) out = y @ W_out, full-K proven core, fp32 direct: 64x8 = 512 blocks.
    gemm_out_kernel<<<dim3(ROWS / 128, D_MODEL / 128), 256, 0, stream>>>(
        y, W_outT, out);
}

// Round 5
// 411.504 us; speedup vs baseline: 1.0790x; 1.0085x over previous
//
#include <hip/hip_runtime.h>
#include <hip/hip_bf16.h>
#include <math.h>

#define D_MODEL   1024
#define D_STATE   128
#define HEADDIM   64
#define CHUNK     64
#define D_INNER   2048
#define NHEADS    32
#define D_IN_PROJ 4384   // 2*2048 + 2*128 + 32
#define CONV_CH   2304   // 2048 + 256
#define RCOLS     2336   // CONV_CH + NHEADS (xBC-raw + dt-raw columns)
#define WINT_ROWS 4480   // D_IN_PROJ padded so col-tile 34 stays in-bounds
#define BATCH     2
#define SEQ       4096
#define NCHUNK    64     // SEQ / CHUNK
#define ROWS      (BATCH*SEQ)   // 8192
#define EPS_RMS   1e-5f

typedef __hip_bfloat16 bf16;
typedef __bf16 bf16x8_t __attribute__((ext_vector_type(8)));
typedef float  f32x4_t  __attribute__((ext_vector_type(4)));

__device__ __forceinline__ float siluf_(float x){ return x/(1.f+expf(-x)); }
__device__ __forceinline__ void  stf(float* p, float v){ *p = v; }
__device__ __forceinline__ void  stf(bf16* p, float v){ *p = __float2bfloat16(v); }

__device__ __forceinline__ __bf16 tobf(float v){
    __hip_bfloat16 t = __float2bfloat16(v);
    return *reinterpret_cast<__bf16*>(&t);
}
__device__ __forceinline__ unsigned short bfbits(float v){
    __hip_bfloat16 t = __float2bfloat16(v);
    return *reinterpret_cast<unsigned short*>(&t);
}
__device__ __forceinline__ float bfbits2f(unsigned short u){
    union { unsigned u; float f; } cv; cv.u = ((unsigned)u) << 16; return cv.f;
}

// async global->LDS, 16 B per lane; LDS dest is wave-uniform base + lane*16.
__device__ __forceinline__ void async16(const void* g, void* l) {
    __builtin_amdgcn_global_load_lds(
        (const __attribute__((address_space(1))) unsigned int*)g,
        (__attribute__((address_space(3))) unsigned int*)l, 16, 0, 0);
}

// ---------------------------------------------------------------------------
// Shared MFMA K-loop body (m97 structure): 128x128 tile, BK=32, 4 waves,
// wave = 64x64 patch = 4x4 of 16x16x32 tiles.  (Round-0/4 proven: ~98 us zr.)
// ---------------------------------------------------------------------------
struct GemmCore {
    f32x4_t acc[4][4];
    __device__ __forceinline__ void run(const bf16* __restrict__ A, int lda,
                                        const bf16* __restrict__ Bt, int ldb,
                                        int row0, int col0, int k0, int k1,
                                        __bf16* As, __bf16* Bs,
                                        int wave, int lane) {
        const int quad = lane >> 4, l16 = lane & 15;
        const int wr = (wave >> 1) * 64, wc = (wave & 1) * 64;
#pragma unroll
        for (int i = 0; i < 4; ++i)
#pragma unroll
            for (int j = 0; j < 4; ++j) acc[i][j] = (f32x4_t){0.f, 0.f, 0.f, 0.f};
        const int ca0 = wave * 2, ca1 = wave * 2 + 1;
        const int srow = lane >> 2, scol = (lane & 3) * 8;
        const bf16* Ag0 = A  + (size_t)(row0 + ca0 * 16 + srow) * lda + scol;
        const bf16* Ag1 = A  + (size_t)(row0 + ca1 * 16 + srow) * lda + scol;
        const bf16* Bg0 = Bt + (size_t)(col0 + ca0 * 16 + srow) * ldb + scol;
        const bf16* Bg1 = Bt + (size_t)(col0 + ca1 * 16 + srow) * ldb + scol;
        __bf16* Al0 = As + ca0 * 512;
        __bf16* Al1 = As + ca1 * 512;
        __bf16* Bl0 = Bs + ca0 * 512;
        __bf16* Bl1 = Bs + ca1 * 512;
        for (int kk = k0; kk < k1; kk += 32) {
            async16(Ag0 + kk, Al0);
            async16(Ag1 + kk, Al1);
            async16(Bg0 + kk, Bl0);
            async16(Bg1 + kk, Bl1);
            __syncthreads();
            bf16x8_t af[4], bfr[4];
#pragma unroll
            for (int mi = 0; mi < 4; ++mi)
                af[mi] = *(const bf16x8_t*)(As + (wr + mi * 16 + l16) * 32 + quad * 8);
#pragma unroll
            for (int ni = 0; ni < 4; ++ni)
                bfr[ni] = *(const bf16x8_t*)(Bs + (wc + ni * 16 + l16) * 32 + quad * 8);
#pragma unroll
            for (int mi = 0; mi < 4; ++mi)
#pragma unroll
                for (int ni = 0; ni < 4; ++ni)
                    acc[mi][ni] = __builtin_amdgcn_mfma_f32_16x16x32_bf16(
                        af[mi], bfr[ni], acc[mi][ni], 0, 0, 0);
            __syncthreads();
        }
    }
};

// Fused Z|R GEMM: one dispatch over all 35 col-tiles of W_inT.
__global__ __launch_bounds__(256) void gemm_zr_fused(const bf16* __restrict__ A,
                                                     const bf16* __restrict__ Bt,
                                                     bf16* __restrict__ Z,
                                                     bf16* __restrict__ R) {
    __shared__ __align__(16) __bf16 As[128 * 32];
    __shared__ __align__(16) __bf16 Bs[128 * 32];
    const int tid = threadIdx.x, wave = tid >> 6, lane = tid & 63;
    const int quad = lane >> 4, l16 = lane & 15;
    const int row0 = blockIdx.x * 128;
    const int ct   = blockIdx.y;
    GemmCore g;
    g.run(A, D_MODEL, Bt, D_MODEL, row0, ct * 128, 0, D_MODEL, As, Bs, wave, lane);

    bf16* Cp; int ldc_, cl0, ncols;
    if (ct < 16) { Cp = Z; ldc_ = D_INNER; cl0 = ct * 128;          ncols = D_INNER; }
    else         { Cp = R; ldc_ = RCOLS;   cl0 = ct * 128 - D_INNER; ncols = RCOLS; }
    const int wr = (wave >> 1) * 64, wc = (wave & 1) * 64;
#pragma unroll
    for (int ni = 0; ni < 4; ++ni) {
        int gc = cl0 + wc + ni * 16 + l16;
        if (gc >= ncols) continue;
#pragma unroll
        for (int mi = 0; mi < 4; ++mi)
#pragma unroll
            for (int r = 0; r < 4; ++r) {
                int gr = row0 + wr + mi * 16 + quad * 4 + r;
                stf(&Cp[(size_t)gr * ldc_ + gc], g.acc[mi][ni][r]);
            }
    }
}

// Out GEMM, full K=2048, fp32 direct to out. grid (64, 8) = 512 blocks.
__global__ __launch_bounds__(256) void gemm_out_kernel(const bf16* __restrict__ A,
                                                       const bf16* __restrict__ Bt,
                                                       float* __restrict__ out) {
    __shared__ __align__(16) __bf16 As[128 * 32];
    __shared__ __align__(16) __bf16 Bs[128 * 32];
    const int tid = threadIdx.x, wave = tid >> 6, lane = tid & 63;
    const int quad = lane >> 4, l16 = lane & 15;
    const int row0 = blockIdx.x * 128;
    const int col0 = blockIdx.y * 128;
    GemmCore g;
    g.run(A, D_INNER, Bt, D_INNER, row0, col0, 0, D_INNER, As, Bs, wave, lane);
    const int wr = (wave >> 1) * 64, wc = (wave & 1) * 64;
#pragma unroll
    for (int ni = 0; ni < 4; ++ni) {
        int gc = col0 + wc + ni * 16 + l16;
#pragma unroll
        for (int mi = 0; mi < 4; ++mi)
#pragma unroll
            for (int r = 0; r < 4; ++r) {
                int gr = row0 + wr + mi * 16 + quad * 4 + r;
                out[(size_t)gr * D_MODEL + gc] = g.acc[mi][ni][r];
            }
    }
}

// ---------------------------------------------------------------------------
// Merged prep: [0,8192) u->bf16 cast | [8192,12672) W_in^T | [12672,14720)
// W_out^T | [14720,14756) conv_w relayout.  One dispatch instead of four.
// ---------------------------------------------------------------------------
__global__ __launch_bounds__(256) void prep_all_kernel(const float* __restrict__ u,
                                                       bf16* __restrict__ u_bf16,
                                                       const float* __restrict__ W_in,
                                                       bf16* __restrict__ W_inT,
                                                       const float* __restrict__ W_out,
                                                       bf16* __restrict__ W_outT,
                                                       const float* __restrict__ conv_w,
                                                       bf16* __restrict__ Wc) {
    __shared__ float tile[32][33];
    int bid = blockIdx.x;
    const int tid = threadIdx.x;

    auto do_transpose = [&](const float* W, bf16* Wt, int R, int C, int c0, int r0) {
        int tx = tid & 31, ty = tid >> 5;
        for (int i = ty; i < 32; i += 8) {
            int r = r0 + i, c = c0 + tx;
            tile[i][tx] = (c < C) ? W[(size_t)r * C + c] : 0.f;
        }
        __syncthreads();
        for (int i = ty; i < 32; i += 8) {
            int c = c0 + i, r = r0 + tx;
            stf(&Wt[(size_t)c * R + r], tile[tx][i]);
        }
    };

    if (bid < 8192) {                       // u fp32 -> bf16, 4 elems/thread
        int i = bid * 256 + tid;            // ROWS*D_MODEL/4 exactly
        float4 v = ((const float4*)u)[i];
        u_bf16[i * 4 + 0] = __float2bfloat16(v.x);
        u_bf16[i * 4 + 1] = __float2bfloat16(v.y);
        u_bf16[i * 4 + 2] = __float2bfloat16(v.z);
        u_bf16[i * 4 + 3] = __float2bfloat16(v.w);
        return;
    }
    bid -= 8192;
    if (bid < (WINT_ROWS / 32) * (D_MODEL / 32)) {      // 140*32 = 4480
        int bx = bid % (WINT_ROWS / 32), by = bid / (WINT_ROWS / 32);
        do_transpose(W_in, W_inT, D_MODEL, D_IN_PROJ, bx * 32, by * 32);
        return;
    }
    bid -= (WINT_ROWS / 32) * (D_MODEL / 32);
    if (bid < (D_MODEL / 32) * (D_INNER / 32)) {        // 32*64 = 2048
        int bx = bid % (D_MODEL / 32), by = bid / (D_MODEL / 32);
        do_transpose(W_out, W_outT, D_INNER, D_MODEL, bx * 32, by * 32);
        return;
    }
    bid -= (D_MODEL / 32) * (D_INNER / 32);
    int i = bid * 256 + tid;                // CONV_CH*4 = 9216 (36 blocks exact)
    if (i < CONV_CH * 4) {
        int ch = i >> 2, k = i & 3;
        Wc[k * CONV_CH + ch] = __float2bfloat16(conv_w[ch * 4 + k]);
    }
}

// ---------------------------------------------------------------------------
// Depthwise causal conv (k=4) + bias + SiLU.  One thread = 4 rows x 8 channels.
// ---------------------------------------------------------------------------
__global__ __launch_bounds__(256) void conv_silu_kernel(const bf16* __restrict__ R,
                                                        const bf16* __restrict__ Wc,
                                                        const float* __restrict__ conv_b,
                                                        bf16* __restrict__ xBC) {
    int idx = blockIdx.x * 256 + threadIdx.x;   // ROWS/4 * 288 exactly
    int rq = idx / 288;
    int g = idx - rq * 288;
    int ch0 = g * 8;
    int row0 = rq * 4;
    int l0 = row0 & (SEQ - 1);

    uint4 rv[7];
#pragma unroll
    for (int j = 0; j < 7; ++j) {
        int ls = l0 - 3 + j;
        rv[j] = (ls >= 0) ? *(const uint4*)&R[(size_t)(row0 - 3 + j) * RCOLS + ch0]
                          : make_uint4(0u, 0u, 0u, 0u);
    }
    uint4 wv[4];
#pragma unroll
    for (int k = 0; k < 4; ++k)
        wv[k] = *(const uint4*)&Wc[k * CONV_CH + ch0];
    float4 b0 = ((const float4*)conv_b)[ch0 / 4];
    float4 b1 = ((const float4*)conv_b)[ch0 / 4 + 1];
    const float bias[8] = {b0.x, b0.y, b0.z, b0.w, b1.x, b1.y, b1.z, b1.w};
    float wf[4][8];
#pragma unroll
    for (int k = 0; k < 4; ++k) {
        const unsigned* wp = (const unsigned*)&wv[k];
#pragma unroll
        for (int j2 = 0; j2 < 4; ++j2) {
            wf[k][2 * j2]     = bfbits2f((unsigned short)(wp[j2] & 0xffff));
            wf[k][2 * j2 + 1] = bfbits2f((unsigned short)(wp[j2] >> 16));
        }
    }
#pragma unroll
    for (int j = 0; j < 4; ++j) {
        float acc[8];
#pragma unroll
        for (int cc = 0; cc < 8; ++cc) acc[cc] = bias[cc];
#pragma unroll
        for (int k = 0; k < 4; ++k) {
            const unsigned* vp = (const unsigned*)&rv[j + k];
#pragma unroll
            for (int j2 = 0; j2 < 4; ++j2) {
                unsigned v = vp[j2];
                acc[2 * j2]     += wf[k][2 * j2]     * bfbits2f((unsigned short)(v & 0xffff));
                acc[2 * j2 + 1] += wf[k][2 * j2 + 1] * bfbits2f((unsigned short)(v >> 16));
            }
        }
        unsigned o[4];
#pragma unroll
        for (int j2 = 0; j2 < 4; ++j2)
            o[j2] = (unsigned)bfbits(siluf_(acc[2 * j2])) |
                    ((unsigned)bfbits(siluf_(acc[2 * j2 + 1])) << 16);
        *(uint4*)&xBC[(size_t)(row0 + j) * CONV_CH + ch0] = make_uint4(o[0], o[1], o[2], o[3]);
    }
}

// dt[row][h0..h0+7] = softplus(R[row][CONV_CH+h] + dt_bias[h]), vectorized.
__global__ void dt_kernel(const bf16* __restrict__ R,
                          const float* __restrict__ dt_bias,
                          float* __restrict__ dtb) {
    int i = blockIdx.x * 256 + threadIdx.x;         // ROWS*4 exactly
    int row = i >> 2, h0 = (i & 3) * 8;
    uint4 v = *(const uint4*)&R[(size_t)row * RCOLS + CONV_CH + h0];
    float4 bia0 = ((const float4*)dt_bias)[h0 / 4];
    float4 bia1 = ((const float4*)dt_bias)[h0 / 4 + 1];
    const unsigned vv[4] = {v.x, v.y, v.z, v.w};
    const float bb[8] = {bia0.x, bia0.y, bia0.z, bia0.w, bia1.x, bia1.y, bia1.z, bia1.w};
    float o[8];
#pragma unroll
    for (int j = 0; j < 4; ++j) {
        float a = bfbits2f((unsigned short)(vv[j] & 0xffff)) + bb[2*j];
        float c = bfbits2f((unsigned short)(vv[j] >> 16)) + bb[2*j+1];
        o[2*j]   = (a > 20.f) ? a : log1pf(expf(a));
        o[2*j+1] = (c > 20.f) ? c : log1pf(expf(c));
    }
    float* dp = &dtb[(size_t)row * NHEADS + h0];
    *(float4*)dp       = make_float4(o[0], o[1], o[2], o[3]);
    *(float4*)(dp + 4) = make_float4(o[4], o[5], o[6], o[7]);
}

// Per (b,c,h): inclusive cumsum of A[h]*dt over the 64-long chunk.
// Lane 63 additionally writes decs[bch] = exp(total) for the scan.
__global__ void acum_kernel(const float* __restrict__ dtb,
                            const float* __restrict__ A_log,
                            float* __restrict__ Acum,
                            float* __restrict__ decs) {
    int bch = blockIdx.x;
    int h = bch & 31;
    int bc = bch >> 5;
    int c = bc & 63, b = bc >> 6;
    int row0 = b * SEQ + c * CHUNK;
    __shared__ float sh[64];
    int l = threadIdx.x;
    float Ah = -expf(A_log[h]);
    sh[l] = Ah * dtb[(size_t)(row0 + l) * NHEADS + h];
    __syncthreads();
    float s = 0.f;
    for (int j = 0; j <= l; ++j) s += sh[j];
    Acum[(size_t)bch * 64 + l] = s;
    if (l == 63) decs[bch] = expf(s);
}

// ---------------------------------------------------------------------------
// MFMA chunk-states: S[p][n] = sum_l (x[l,p]*dt[l]*dec[l]) * B[l,n].
// LDS transposes use l-pair-packed b32 writes (half the LDS-write insts).
// ---------------------------------------------------------------------------
__global__ __launch_bounds__(256) void states_mfma_kernel(const bf16* __restrict__ xBC,
                                                          const float* __restrict__ dtb,
                                                          const float* __restrict__ Acum,
                                                          bf16* __restrict__ states) {
    __shared__ __align__(16) __bf16 BsT[128 * 72];      // [n][l], stride 72 (144 B)
    __shared__ __align__(16) __bf16 xdT[4][64 * 72];    // per-wave [p][l]
    __shared__ float dtdec[4][64];
    int bcq = blockIdx.x;                 // (b*64+c)*8 + hq
    int hq = bcq & 7, bc = bcq >> 3;
    int c = bc & 63, b = bc >> 6;
    int tid = threadIdx.x, wave = tid >> 6, lane = tid & 63;
    int h = hq * 4 + wave;
    int bch = bc * 32 + h;
    int row0 = b * SEQ + c * CHUNK;
    int quad = lane >> 4, l16 = lane & 15;

    {
        float alast = Acum[(size_t)bch * 64 + 63];
        float a = Acum[(size_t)bch * 64 + lane];
        dtdec[wave][lane] = dtb[(size_t)(row0 + lane) * NHEADS + h] * expf(alast - a);
    }
    __syncthreads();
    // BsT fill: 2 l x 2 n per thread-iter, packed b32 writes.
    for (int it = 0; it < 8; ++it) {
        int i2 = tid + 256 * it;            // 0..2047
        int l0 = (i2 >> 6) * 2;
        int n0 = (i2 & 63) * 2;
        unsigned v0 = *(const unsigned*)&xBC[(size_t)(row0 + l0    ) * CONV_CH + D_INNER + n0];
        unsigned v1 = *(const unsigned*)&xBC[(size_t)(row0 + l0 + 1) * CONV_CH + D_INNER + n0];
        *(unsigned*)&BsT[(n0    ) * 72 + l0] = (v0 & 0xffffu) | (v1 << 16);
        *(unsigned*)&BsT[(n0 + 1) * 72 + l0] = (v0 >> 16) | (v1 & 0xffff0000u);
    }
    // xdT fill: 2 l x 2 p per lane-iter, scaled, packed b32 writes.
    for (int it = 0; it < 16; ++it) {
        int l0 = 4 * it + ((lane >> 5) << 1);
        int p0 = (lane & 31) * 2;
        unsigned v0 = *(const unsigned*)&xBC[(size_t)(row0 + l0    ) * CONV_CH + h * 64 + p0];
        unsigned v1 = *(const unsigned*)&xBC[(size_t)(row0 + l0 + 1) * CONV_CH + h * 64 + p0];
        float f0 = dtdec[wave][l0], f1 = dtdec[wave][l0 + 1];
        unsigned w0 = (unsigned)bfbits(bfbits2f((unsigned short)(v0 & 0xffff)) * f0)
                    | ((unsigned)bfbits(bfbits2f((unsigned short)(v1 & 0xffff)) * f1) << 16);
        unsigned w1 = (unsigned)bfbits(bfbits2f((unsigned short)(v0 >> 16)) * f0)
                    | ((unsigned)bfbits(bfbits2f((unsigned short)(v1 >> 16)) * f1) << 16);
        *(unsigned*)&xdT[wave][(p0    ) * 72 + l0] = w0;
        *(unsigned*)&xdT[wave][(p0 + 1) * 72 + l0] = w1;
    }
    __syncthreads();

    f32x4_t acc[4][8];
#pragma unroll
    for (int i = 0; i < 4; ++i)
#pragma unroll
        for (int j = 0; j < 8; ++j) acc[i][j] = (f32x4_t){0.f, 0.f, 0.f, 0.f};
#pragma unroll
    for (int ks = 0; ks < 2; ++ks) {
        bf16x8_t a[4], bb[8];
#pragma unroll
        for (int mi = 0; mi < 4; ++mi)
            a[mi] = *(const bf16x8_t*)(&xdT[wave][(mi * 16 + l16) * 72 + ks * 32 + quad * 8]);
#pragma unroll
        for (int ni = 0; ni < 8; ++ni)
            bb[ni] = *(const bf16x8_t*)(&BsT[(ni * 16 + l16) * 72 + ks * 32 + quad * 8]);
#pragma unroll
        for (int mi = 0; mi < 4; ++mi)
#pragma unroll
            for (int ni = 0; ni < 8; ++ni)
                acc[mi][ni] = __builtin_amdgcn_mfma_f32_16x16x32_bf16(
                    a[mi], bb[ni], acc[mi][ni], 0, 0, 0);
    }
#pragma unroll
    for (int ni = 0; ni < 8; ++ni) {
        int n = ni * 16 + l16;
#pragma unroll
        for (int mi = 0; mi < 4; ++mi)
#pragma unroll
            for (int r = 0; r < 4; ++r) {
                int p = mi * 16 + quad * 4 + r;
                stf(&states[(size_t)bch * 8192 + p * 128 + n], acc[mi][ni][r]);
            }
    }
}

// Inter-chunk scan (in place), 4 states/thread, fp32 carry.
// Software-pipelined: chunk c+1's load issues before chunk c's store/update;
// dec factors precomputed (decs) — no expf / Acum load in the chain.
__global__ void scan_kernel(const float* __restrict__ decs,
                            bf16* __restrict__ states) {
    int i = blockIdx.x * 256 + threadIdx.x;     // BATCH*NHEADS*2048 exactly
    int pn0 = (i & 2047) * 4;
    int bh = i >> 11;
    int h = bh & 31, b = bh >> 5;
    int bch0 = b * NCHUNK * NHEADS + h;
    const size_t cstride = (size_t)NHEADS * 8192;   // elems between chunks
    float carry[4] = {0.f, 0.f, 0.f, 0.f};
    bf16* sp = &states[(size_t)bch0 * 8192 + pn0];
    uint2 v = *(const uint2*)sp;
    for (int c = 0; c < NCHUNK; ++c) {
        bf16* spn = sp + ((c + 1 < NCHUNK) ? cstride : 0);
        uint2 vn = *(const uint2*)spn;          // prefetch (safe: clamped)
        float dec = decs[bch0 + c * NHEADS];
        uint2 o;
        o.x = (unsigned)bfbits(carry[0]) | ((unsigned)bfbits(carry[1]) << 16);
        o.y = (unsigned)bfbits(carry[2]) | ((unsigned)bfbits(carry[3]) << 16);
        *(uint2*)sp = o;
        carry[0] = carry[0] * dec + bfbits2f((unsigned short)(v.x & 0xffff));
        carry[1] = carry[1] * dec + bfbits2f((unsigned short)(v.x >> 16));
        carry[2] = carry[2] * dec + bfbits2f((unsigned short)(v.y & 0xffff));
        carry[3] = carry[3] * dec + bfbits2f((unsigned short)(v.y >> 16));
        sp = spn; v = vn;
    }
}

// ---------------------------------------------------------------------------
// MFMA Y (gchunk fused): per (b,c,h) one wave.
// ---------------------------------------------------------------------------
__global__ __launch_bounds__(64) void y_mfma_kernel(const bf16* __restrict__ xBC,
                                                    const float* __restrict__ dtb,
                                                    const float* __restrict__ Acum,
                                                    const bf16* __restrict__ states,
                                                    const float* __restrict__ Dv,
                                                    bf16* __restrict__ y) {
    __shared__ __align__(16) __bf16 Mm[64 * 72];
    __shared__ __align__(16) __bf16 xsT[64 * 72];
    __shared__ float acs[64], dtss[64], sdos[64];
    int bch = blockIdx.x;
    int h = bch & 31, bc = bch >> 5;
    int c = bc & 63, b = bc >> 6;
    int row0 = b * SEQ + c * CHUNK;
    int lane = threadIdx.x;
    int quad = lane >> 4, l16 = lane & 15;

    {
        float a = Acum[(size_t)bch * 64 + lane];
        acs[lane] = a;
        sdos[lane] = expf(a);
        dtss[lane] = dtb[(size_t)(row0 + lane) * NHEADS + h];
    }
    // x transpose into LDS: 2 l x 2 p per lane-iter, packed b32 writes.
    for (int it = 0; it < 16; ++it) {
        int l0 = 4 * it + ((lane >> 5) << 1);
        int p0 = (lane & 31) * 2;
        unsigned v0 = *(const unsigned*)&xBC[(size_t)(row0 + l0    ) * CONV_CH + h * 64 + p0];
        unsigned v1 = *(const unsigned*)&xBC[(size_t)(row0 + l0 + 1) * CONV_CH + h * 64 + p0];
        *(unsigned*)&xsT[(p0    ) * 72 + l0] = (v0 & 0xffffu) | (v1 << 16);
        *(unsigned*)&xsT[(p0 + 1) * 72 + l0] = (v0 >> 16) | (v1 & 0xffff0000u);
    }
    __syncthreads();

    // ---- Phase A: G via MFMA (only mi >= ni tiles; upper tiles are masked)
    f32x4_t gacc[4][4];
#pragma unroll
    for (int i = 0; i < 4; ++i)
#pragma unroll
        for (int j = 0; j < 4; ++j) gacc[i][j] = (f32x4_t){0.f, 0.f, 0.f, 0.f};
#pragma unroll
    for (int ks = 0; ks < 4; ++ks) {
        bf16x8_t a[4], bb[4];
#pragma unroll
        for (int mi = 0; mi < 4; ++mi)
            a[mi] = *(const bf16x8_t*)&xBC[(size_t)(row0 + mi * 16 + l16) * CONV_CH +
                                           D_INNER + D_STATE + ks * 32 + quad * 8];
#pragma unroll
        for (int ni = 0; ni < 4; ++ni)
            bb[ni] = *(const bf16x8_t*)&xBC[(size_t)(row0 + ni * 16 + l16) * CONV_CH +
                                            D_INNER + ks * 32 + quad * 8];
#pragma unroll
        for (int mi = 0; mi < 4; ++mi)
#pragma unroll
            for (int ni = 0; ni <= mi; ++ni)
                gacc[mi][ni] = __builtin_amdgcn_mfma_f32_16x16x32_bf16(
                    a[mi], bb[ni], gacc[mi][ni], 0, 0, 0);
    }
    // Build Mm from gacc: l = mi*16+quad*4+r, s = ni*16+l16.
#pragma unroll
    for (int ni = 0; ni < 4; ++ni) {
        int s = ni * 16 + l16;
        float ds = dtss[s], as = acs[s];
#pragma unroll
        for (int mi = 0; mi < 4; ++mi)
#pragma unroll
            for (int r = 0; r < 4; ++r) {
                int l = mi * 16 + quad * 4 + r;
                float coef = (s <= l) ? gacc[mi][ni][r] * ds * expf(acs[l] - as) : 0.f;
                Mm[l * 72 + s] = tobf(coef);
            }
    }
    __syncthreads();

    f32x4_t acc[4][4];
#pragma unroll
    for (int i = 0; i < 4; ++i)
#pragma unroll
        for (int j = 0; j < 4; ++j) acc[i][j] = (f32x4_t){0.f, 0.f, 0.f, 0.f};

    // ---- Phase 1: Y_diag = Mm @ x
#pragma unroll
    for (int ks = 0; ks < 2; ++ks) {
        bf16x8_t a[4], bb[4];
#pragma unroll
        for (int mi = 0; mi < 4; ++mi)
            a[mi] = *(const bf16x8_t*)(&Mm[(mi * 16 + l16) * 72 + ks * 32 + quad * 8]);
#pragma unroll
        for (int ni = 0; ni < 4; ++ni)
            bb[ni] = *(const bf16x8_t*)(&xsT[(ni * 16 + l16) * 72 + ks * 32 + quad * 8]);
#pragma unroll
        for (int mi = 0; mi < 4; ++mi)
#pragma unroll
            for (int ni = 0; ni < 4; ++ni)
                acc[mi][ni] = __builtin_amdgcn_mfma_f32_16x16x32_bf16(
                    a[mi], bb[ni], acc[mi][ni], 0, 0, 0);
    }
    // ---- Phase 2: Y_off = (C*sdo) @ states^T
    float sdo_mi[4];
#pragma unroll
    for (int mi = 0; mi < 4; ++mi) sdo_mi[mi] = sdos[mi * 16 + l16];
#pragma unroll
    for (int ks = 0; ks < 4; ++ks) {
        bf16x8_t a[4], bb[4];
#pragma unroll
        for (int mi = 0; mi < 4; ++mi) {
            const unsigned* cp = (const unsigned*)&xBC[(size_t)(row0 + mi * 16 + l16) * CONV_CH
                                                       + D_INNER + D_STATE + ks * 32 + quad * 8];
            float sc = sdo_mi[mi];
#pragma unroll
            for (int jj = 0; jj < 4; ++jj) {
                unsigned v = cp[jj];
                a[mi][2 * jj    ] = tobf(bfbits2f((unsigned short)(v & 0xffff)) * sc);
                a[mi][2 * jj + 1] = tobf(bfbits2f((unsigned short)(v >> 16)) * sc);
            }
        }
#pragma unroll
        for (int ni = 0; ni < 4; ++ni)
            bb[ni] = *(const bf16x8_t*)&states[(size_t)bch * 8192 + (ni * 16 + l16) * 128
                                               + ks * 32 + quad * 8];
#pragma unroll
        for (int mi = 0; mi < 4; ++mi)
#pragma unroll
            for (int ni = 0; ni < 4; ++ni)
                acc[mi][ni] = __builtin_amdgcn_mfma_f32_16x16x32_bf16(
                    a[mi], bb[ni], acc[mi][ni], 0, 0, 0);
    }
    float Dh = Dv[h];
#pragma unroll
    for (int ni = 0; ni < 4; ++ni) {
        int p = ni * 16 + l16;
#pragma unroll
        for (int mi = 0; mi < 4; ++mi)
#pragma unroll
            for (int r = 0; r < 4; ++r) {
                int l = mi * 16 + quad * 4 + r;
                float xv = bfbits2f(*(const unsigned short*)&xsT[p * 72 + l]);
                stf(&y[(size_t)(row0 + l) * D_INNER + h * 64 + p],
                    acc[mi][ni][r] + Dh * xv);
            }
    }
}

// Per row: v = y * silu(z); y = v * rsqrt(mean(v^2)+eps) * norm_w.
__global__ __launch_bounds__(256) void gate_norm_kernel(const bf16* __restrict__ Z,
                                                        const float* __restrict__ nw,
                                                        bf16* __restrict__ y) {
    int row = blockIdx.x;
    int tid = threadIdx.x;
    int col0 = tid * 8;
    uint4 zv = *(const uint4*)&Z[(size_t)row * D_INNER + col0];
    uint4 yv = *(const uint4*)&y[(size_t)row * D_INNER + col0];
    const unsigned zz[4] = {zv.x, zv.y, zv.z, zv.w};
    const unsigned yy[4] = {yv.x, yv.y, yv.z, yv.w};
    float vals[8];
    float local = 0.f;
#pragma unroll
    for (int j = 0; j < 4; ++j) {
        float z0 = bfbits2f((unsigned short)(zz[j] & 0xffff));
        float z1 = bfbits2f((unsigned short)(zz[j] >> 16));
        float y0 = bfbits2f((unsigned short)(yy[j] & 0xffff));
        float y1 = bfbits2f((unsigned short)(yy[j] >> 16));
        float v0 = y0 * siluf_(z0);
        float v1 = y1 * siluf_(z1);
        vals[2*j] = v0; vals[2*j+1] = v1;
        local += v0 * v0 + v1 * v1;
    }
#pragma unroll
    for (int off = 32; off; off >>= 1) local += __shfl_down(local, off, 64);
    __shared__ float wsum[4];
    if ((tid & 63) == 0) wsum[tid >> 6] = local;
    __syncthreads();
    float total = wsum[0] + wsum[1] + wsum[2] + wsum[3];
    float scale = rsqrtf(total / (float)D_INNER + EPS_RMS);
    float4 w0 = ((const float4*)nw)[col0 / 4];
    float4 w1 = ((const float4*)nw)[col0 / 4 + 1];
    const float ww[8] = {w0.x, w0.y, w0.z, w0.w, w1.x, w1.y, w1.z, w1.w};
    unsigned o[4];
#pragma unroll
    for (int j = 0; j < 4; ++j)
        o[j] = (unsigned)bfbits(vals[2*j] * scale * ww[2*j]) |
               ((unsigned)bfbits(vals[2*j+1] * scale * ww[2*j+1]) << 16);
    *(uint4*)&y[(size_t)row * D_INNER + col0] = make_uint4(o[0], o[1], o[2], o[3]);
}

// ---------------------------------------------------------------------------
extern "C" void kernel_launch(void* const* d_in, const int* in_sizes, int n_in,
                              void* d_out, int out_size, void* d_ws, size_t ws_size,
                              hipStream_t stream) {
    const float* u       = (const float*)d_in[0];
    const float* W_in    = (const float*)d_in[1];
    const float* conv_w  = (const float*)d_in[2];
    const float* conv_b  = (const float*)d_in[3];
    const float* dt_bias = (const float*)d_in[4];
    const float* A_log   = (const float*)d_in[5];
    const float* Dv      = (const float*)d_in[6];
    const float* norm_w  = (const float*)d_in[7];
    const float* W_out   = (const float*)d_in[8];
    float* out = (float*)d_out;

    const size_t sz_xBC    = (size_t)ROWS * CONV_CH * 2;
    const size_t sz_Z      = (size_t)ROWS * D_INNER * 2;
    const size_t sz_y      = (size_t)ROWS * D_INNER * 2;
    const size_t sz_states = (size_t)BATCH * NCHUNK * NHEADS * 8192 * 2;  // 67.1 MB
    const size_t sz_dtb    = (size_t)ROWS * NHEADS * 4;
    const size_t sz_Acum   = (size_t)BATCH * NCHUNK * NHEADS * 64 * 4;
    const size_t sz_decs   = (size_t)BATCH * NCHUNK * NHEADS * 4;
    const size_t sz_WinT   = (size_t)WINT_ROWS * D_MODEL * 2;
    const size_t sz_WoutT  = (size_t)D_MODEL * D_INNER * 2;
    const size_t sz_Wc     = (size_t)CONV_CH * 4 * 2;
    const size_t need = sz_xBC + sz_Z + sz_y + sz_states + sz_dtb + sz_Acum +
                        sz_decs + sz_WinT + sz_WoutT + sz_Wc;
    if (ws_size < need) {
        hipMemsetAsync(d_out, 0, (size_t)out_size * sizeof(float), stream);
        return;
    }
    char* ws = (char*)d_ws;
    size_t off = 0;
    bf16*  xBC    = (bf16*) (ws + off); off += sz_xBC;
    bf16*  Z      = (bf16*) (ws + off); off += sz_Z;
    bf16*  y      = (bf16*) (ws + off); off += sz_y;
    bf16*  states = (bf16*) (ws + off); off += sz_states;
    float* dtb    = (float*)(ws + off); off += sz_dtb;
    float* Acum   = (float*)(ws + off); off += sz_Acum;
    float* decs   = (float*)(ws + off); off += sz_decs;
    bf16*  W_inT  = (bf16*) (ws + off); off += sz_WinT;
    bf16*  W_outT = (bf16*) (ws + off); off += sz_WoutT;
    bf16*  Wc     = (bf16*) (ws + off); off += sz_Wc;
    // Aliases of the states region (67.1 MB), dead before their overwrite:
    //  - R (38.3 MB) + u_bf16 (16.8 MB): dead before states_mfma_kernel.
    bf16*  R        = states;
    bf16*  u_bf16   = (bf16*)((char*)states + (size_t)ROWS * RCOLS * 2);

    // 0) merged prep (cast + both transposes + conv_w relayout): one dispatch
    const int prep_blocks = 8192 + (WINT_ROWS / 32) * (D_MODEL / 32)
                          + (D_MODEL / 32) * (D_INNER / 32) + 36;   // 14756
    prep_all_kernel<<<prep_blocks, 256, 0, stream>>>(
        u, u_bf16, W_in, W_inT, W_out, W_outT, conv_w, Wc);
    // 1) fused Z|R GEMM: round-0 proven core, 64x35 = 2240 blocks
    gemm_zr_fused<<<dim3(ROWS / 128, 35), 256, 0, stream>>>(u_bf16, W_inT, Z, R);
    // 2) conv + silu (4 rows/thread) ; dt
    conv_silu_kernel<<<ROWS / 4 * 288 / 256, 256, 0, stream>>>(R, Wc, conv_b, xBC);
    dt_kernel<<<ROWS * 4 / 256, 256, 0, stream>>>(R, dt_bias, dtb);
    // 3) per-chunk cumsum of A*dt (+ per-chunk decay factor for the scan)
    acum_kernel<<<BATCH * NCHUNK * NHEADS, 64, 0, stream>>>(dtb, A_log, Acum, decs);
    // 4) per-chunk states (MFMA; overwrites R/u_bf16 aliases — both dead)
    states_mfma_kernel<<<BATCH * NCHUNK * 8, 256, 0, stream>>>(xBC, dtb, Acum, states);
    // 5) inter-chunk scan (pipelined, precomputed decay)
    scan_kernel<<<BATCH * NHEADS * 2048 / 256, 256, 0, stream>>>(decs, states);
    // 6) Y = diag + off + D*x  (MFMA; G computed in-block)
    y_mfma_kernel<<<BATCH * NCHUNK * NHEADS, 64, 0, stream>>>(
        xBC, dtb, Acum, states, Dv, y);
    // 7) gate + RMSNorm
    gate_norm_kernel<<<ROWS, 256, 0, stream>>>(Z, norm_w, y);
    // 8) out = y @ W_out, full-K proven core, fp32 direct: 64x8 = 512 blocks.
    gemm_out_kernel<<<dim3(ROWS / 128, D_MODEL / 128), 256, 0, stream>>>(
        y, W_outT, out);
}